// Round 7
// baseline (1195.830 us; speedup 1.0000x reference)
//
#include <hip/hip_runtime.h>
#include <math.h>

// Problem constants
#define BB 2
#define SS 400
#define II 80
#define HH 128
#define FF 256          // 2*H
#define NN 401          // S+1
#define G4 512          // 4*H
#define MAXSEG 50
#define NCLS 50
#define KH 100          // rows of W1 / Wc1 / Wb1
#define KP 112          // KH padded to 7*16 for MFMA

// d_out layout (floats): scores | cls | bin | pred | prev
#define SCORES_OFF 0
#define CLS_OFF    (BB*NN*NN)
#define BIN_OFF    (CLS_OFF + BB*SS*NCLS)
#define PRED_OFF   (BIN_OFF + BB*SS*2)
#define PREV_OFF   (PRED_OFF + BB)

// workspace layout (float slots)
#define WS_GX      0                          // 2dir*400*2b*512 = 819200 (dead after
                                              // k_lstm_rec; reused as scoresT 321602)
#define WS_RNN     (WS_GX + 4*SS*G4)          // B*S*F
#define WS_CUM     (WS_RNN + BB*SS*FF)        // B*N*F
#define WS_PXD     (WS_CUM + BB*NN*FF)        // B*N*KP
#define WS_PXE     (WS_PXD + BB*NN*KP)
#define WS_PART    (WS_PXE + BB*NN*KP)        // B*16*F
#define WS_WH      (WS_PART + BB*16*FF)       // W1c hi bf16: KP*FF shorts
#define WS_WL      (WS_WH + (KP*FF)/2)
#define WS_W2P     (WS_WL + (KP*FF)/2)        // KP floats
#define WS_B1P     (WS_W2P + KP)              // KP floats
#define WS_WHH     (WS_B1P + KP)              // Wh packed hi bf16: 2*512*128 shorts
#define WS_WHL     (WS_WHH + (2*G4*HH)/2)     // Wh packed lo bf16
// total ~1.57M floats ~6.3MB

typedef __attribute__((ext_vector_type(8))) short short8;
typedef __attribute__((ext_vector_type(4))) float f32x4;

__device__ __forceinline__ float prelu_f(float x, float a) {
    return x >= 0.f ? x : a * x;
}
__device__ __forceinline__ unsigned short f2bf(float x) {
    union { float f; unsigned u; } v; v.f = x;
    unsigned r = v.u + 0x7fffu + ((v.u >> 16) & 1u);   // RNE
    return (unsigned short)(r >> 16);
}
__device__ __forceinline__ float bf2f(unsigned short h) {
    union { unsigned u; float f; } v; v.u = ((unsigned)h) << 16; return v.f;
}
__device__ __forceinline__ float fast_sigmoid(float x) {
    return 1.f / (1.f + __expf(-x));
}
__device__ __forceinline__ float fast_tanh(float x) {
    return 1.f - 2.f / (1.f + __expf(2.f * x));
}

// ---------------- K0: prep W1c bf16 hi/lo + padded W2/b1 -------------------
__global__ void k_prep(const float* __restrict__ W1, const float* __restrict__ W2,
                       const float* __restrict__ b1,
                       short* __restrict__ wh, short* __restrict__ wl,
                       float* __restrict__ w2p, float* __restrict__ b1p) {
    int k = blockIdx.x;        // 0..111
    int f = threadIdx.x;       // 0..255
    float w = (k < KH) ? W1[k * (3 * FF) + f] : 0.f;
    unsigned short hi = f2bf(w);
    unsigned short lo = f2bf(w - bf2f(hi));
    wh[k * FF + f] = (short)hi;
    wl[k * FF + f] = (short)lo;
    if (f == 0) {
        w2p[k] = (k < KH) ? W2[k] : 0.f;
        b1p[k] = (k < KH) ? b1[k] : 0.f;
    }
}

// ---------------- K0b: pack Wh into MFMA-A-ordered bf16 hi/lo --------------
// Packed row m = w*128 + mt*16 + quad*4 + r  <->  orig gate gid = r*128 + u,
// u = w*32 + quad*8 + mt.  k (col) = unit index, unpermuted.
__global__ void k_prep_wh(const float* __restrict__ Wh_f, const float* __restrict__ Wh_b,
                          short* __restrict__ whh, short* __restrict__ whl) {
    int blk = blockIdx.x;           // dir*512 + m
    int m = blk & 511;
    int dir = blk >> 9;
    const float* Wh = dir ? Wh_b : Wh_f;
    int w = m >> 7, rem = m & 127, mt = rem >> 4, rem2 = rem & 15;
    int quad = rem2 >> 2, r = rem2 & 3;
    int u = w * 32 + quad * 8 + mt;
    int gid = r * 128 + u;
    int k = threadIdx.x;            // 0..127
    float v = Wh[gid * HH + k];
    unsigned short hi = f2bf(v);
    unsigned short lo = f2bf(v - bf2f(hi));
    whh[(dir * G4 + m) * HH + k] = (short)hi;
    whl[(dir * G4 + m) * HH + k] = (short)lo;
}

// ---------------- K1: gx (packed gate order) -------------------------------
// gx[((dir*S + t)*2 + b)*512 + m] = b[gid] + x[b, xt, :] . Wi[gid, :]
__global__ void k_lstm_pre(const float* __restrict__ x,
                           const float* __restrict__ Wi_f, const float* __restrict__ b_f,
                           const float* __restrict__ Wi_b, const float* __restrict__ b_b,
                           float* __restrict__ gx) {
    int blk = blockIdx.x;          // db*S + t
    int t = blk % SS;
    int db = blk / SS;             // dir*2 + b
    int b = db & 1, dir = db >> 1;
    const float* Wi = dir ? Wi_b : Wi_f;
    const float* bias = dir ? b_b : b_f;
    int xt = dir ? (SS - 1 - t) : t;

    __shared__ __align__(16) float xr[II];
    int tid = threadIdx.x;
    if (tid < II) xr[tid] = x[(b * SS + xt) * II + tid];
    __syncthreads();

    for (int g = tid; g < G4; g += 256) {
        const float* w = Wi + g * II;
        float acc = bias[g];
#pragma unroll
        for (int i = 0; i < II; i += 4) {
            float4 w4 = *(const float4*)(w + i);
            acc += w4.x * xr[i] + w4.y * xr[i + 1] + w4.z * xr[i + 2] + w4.w * xr[i + 3];
        }
        // packed gate index
        int u = g & 127, r = g >> 7;
        int w_ = u >> 5, rem = u & 31, quad = rem >> 3, mt = rem & 7;
        int m = w_ * 128 + mt * 16 + quad * 4 + r;
        gx[((dir * SS + t) * 2 + b) * G4 + m] = acc;
    }
}

// ---------------- K2: recurrent LSTM via MFMA, 2 blocks (dir), 256 thr -----
// Wave wv covers packed rows [wv*128, wv*128+128) = 8 m-tiles. A-frags (bf16
// hi/lo) live in AGPRs (MFMA reads them directly — no accvgpr_read, unlike
// R4-R6 where fp32 VALU weights got AGPR-parked at 4x instruction cost).
// B = h (bf16 hi/lo) from LDS, col = l15&1 (batch), replicated by addressing.
// D-tile: lane (quad,l15) tile mt holds gates i,f,g,o (rows quad*4+r) of unit
// u = wv*32+quad*8+mt for batch l15&1 -> lane l15>>1==mt does that unit's
// activation locally: NO shuffles, c_state one reg/lane, 100% lane use.
// 3 MFMA combos: Ahi*Bhi + Ahi*Blo + Alo*Bhi (~2^-16 precision).
__global__ __launch_bounds__(256, 1)
void k_lstm_rec(const short* __restrict__ whh, const short* __restrict__ whl,
                const float* __restrict__ gx_all, float* __restrict__ rnn_out) {
    int dir = blockIdx.x;
    int tid = threadIdx.x;
    int wv = tid >> 6;
    int l = tid & 63;
    int quad = l >> 4;
    int l15 = l & 15;
    int c = l15 & 1;          // batch
    int mysel = l15 >> 1;     // which m-tile this lane activates
    int u = wv * 32 + quad * 8 + mysel;
    int mybase = wv * 128 + mysel * 16 + quad * 4;   // packed m of r=0

    // A fragments: 8 m-tiles x 4 k-tiles, hi+lo -> 256 regs (AGPR-resident)
    short8 Ah[8][4], Al[8][4];
#pragma unroll
    for (int mt = 0; mt < 8; ++mt)
#pragma unroll
        for (int kt = 0; kt < 4; ++kt) {
            int idx = (dir * G4 + wv * 128 + mt * 16 + l15) * HH + kt * 32 + quad * 8;
            Ah[mt][kt] = *(const short8*)(whh + idx);
            Al[mt][kt] = *(const short8*)(whl + idx);
        }

    // h double-buffered, bf16 hi/lo, per batch col; 136-short stride (16B-mult)
    __shared__ short hb[2][2][2][136];   // [pb][hi/lo][col][128+pad]
    for (int i = tid; i < 2 * 2 * 2 * 136; i += 256) (&hb[0][0][0][0])[i] = 0;
    float c_state = 0.f;
    __syncthreads();

    const float* gxp = gx_all + dir * SS * 2 * G4;
    float4 gcur = *(const float4*)(gxp + c * G4 + mybase);   // step 0
    int pb = 0;
    for (int step = 0; step < SS; ++step) {
        // B fragments (8-way same-address broadcast across l15 parity groups)
        short8 Bh[4], Bl[4];
        const short* bh_base = &hb[pb][0][c][0];
        const short* bl_base = &hb[pb][1][c][0];
#pragma unroll
        for (int kt = 0; kt < 4; ++kt) {
            Bh[kt] = *(const short8*)(bh_base + kt * 32 + quad * 8);
            Bl[kt] = *(const short8*)(bl_base + kt * 32 + quad * 8);
        }
        f32x4 acc[8];
#pragma unroll
        for (int mt = 0; mt < 8; ++mt) acc[mt] = (f32x4){0.f, 0.f, 0.f, 0.f};
#pragma unroll
        for (int mt = 0; mt < 8; ++mt)
#pragma unroll
            for (int kt = 0; kt < 4; ++kt) {
                acc[mt] = __builtin_amdgcn_mfma_f32_16x16x32_bf16(Ah[mt][kt], Bh[kt], acc[mt], 0, 0, 0);
                acc[mt] = __builtin_amdgcn_mfma_f32_16x16x32_bf16(Ah[mt][kt], Bl[kt], acc[mt], 0, 0, 0);
                acc[mt] = __builtin_amdgcn_mfma_f32_16x16x32_bf16(Al[mt][kt], Bh[kt], acc[mt], 0, 0, 0);
            }
        // select acc[mysel] (3-level cndmask tree, 28 ops)
        f32x4 t0 = (mysel & 1) ? acc[1] : acc[0];
        f32x4 t1 = (mysel & 1) ? acc[3] : acc[2];
        f32x4 t2 = (mysel & 1) ? acc[5] : acc[4];
        f32x4 t3 = (mysel & 1) ? acc[7] : acc[6];
        f32x4 u0 = (mysel & 2) ? t1 : t0;
        f32x4 u1 = (mysel & 2) ? t3 : t2;
        f32x4 g4 = (mysel & 4) ? u1 : u0;
        // prefetch next step's gx
        float4 gnext = make_float4(0.f, 0.f, 0.f, 0.f);
        if (step + 1 < SS)
            gnext = *(const float4*)(gxp + ((step + 1) * 2 + c) * G4 + mybase);
        // activation (r order: 0=i,1=f,2=g,3=o)
        float gi = g4[0] + gcur.x;
        float gf = g4[1] + gcur.y;
        float gg = g4[2] + gcur.z;
        float go = g4[3] + gcur.w;
        c_state = fast_sigmoid(gf) * c_state + fast_sigmoid(gi) * fast_tanh(gg);
        float h = fast_sigmoid(go) * fast_tanh(c_state);
        unsigned short hi = f2bf(h);
        unsigned short lo = f2bf(h - bf2f(hi));
        hb[pb ^ 1][0][c][u] = (short)hi;
        hb[pb ^ 1][1][c][u] = (short)lo;
        int xt = dir ? (SS - 1 - step) : step;
        rnn_out[(c * SS + xt) * FF + dir * HH + u] = h;
        __syncthreads();
        pb ^= 1;
        gcur = gnext;
    }
}

// ---------------- K3: cumsum over time (3 passes) --------------------------
#define CHUNK 25
#define NCH 16
__global__ void k_cum_part(const float* __restrict__ rnn, float* __restrict__ part) {
    int blk = blockIdx.x;           // b*NCH + c
    int c = blk % NCH, b = blk / NCH;
    int f = threadIdx.x;
    float s = 0.f;
    for (int r = 0; r < CHUNK; ++r) s += rnn[(b * SS + c * CHUNK + r) * FF + f];
    part[blk * FF + f] = s;
}
__global__ void k_cum_off(float* __restrict__ part) {
    int b = blockIdx.x;
    int f = threadIdx.x;
    float run = 0.f;
    for (int c = 0; c < NCH; ++c) {
        int idx = (b * NCH + c) * FF + f;
        float tmp = part[idx];
        part[idx] = run;
        run += tmp;
    }
}
__global__ void k_cum_write(const float* __restrict__ rnn, const float* __restrict__ part,
                            float* __restrict__ cum) {
    int blk = blockIdx.x;           // b*NCH + c
    int c = blk % NCH, b = blk / NCH;
    int f = threadIdx.x;
    float run = part[blk * FF + f];
    cum[(b * NN + c * CHUNK) * FF + f] = run;
    for (int idx = 1; idx <= CHUNK; ++idx) {
        run += rnn[(b * SS + c * CHUNK + idx - 1) * FF + f];
        cum[(b * NN + c * CHUNK + idx) * FF + f] = run;
    }
}

// ---------------- K4: fused pxd/pxe (blk<802) + cls/bin heads (blk>=802) ---
__global__ void k_pxde_heads(const float* __restrict__ rnn, const float* __restrict__ W1,
                             const float* __restrict__ a1p,
                             float* __restrict__ pxd, float* __restrict__ pxe,
                             const float* __restrict__ ac1p, const float* __restrict__ Wc1,
                             const float* __restrict__ bc1, const float* __restrict__ ac2p,
                             const float* __restrict__ Wc2, const float* __restrict__ bc2,
                             const float* __restrict__ ab1p, const float* __restrict__ Wb1,
                             const float* __restrict__ bb1, const float* __restrict__ ab2p,
                             const float* __restrict__ Wb2, const float* __restrict__ bb2,
                             float* __restrict__ cls_out, float* __restrict__ bin_out) {
    int blk = blockIdx.x;
    int tid = threadIdx.x;
    if (blk < BB * NN) {
        // ---- pxde path ----
        int n = blk % NN, b = blk / NN;
        float a1 = a1p[0];
        __shared__ __align__(16) float px[FF];
        float rv = (n == 0) ? 0.f : rnn[(b * SS + n - 1) * FF + tid];
        px[tid] = prelu_f(rv, a1);
        __syncthreads();

        if (tid < KH) {
            const float* w = W1 + tid * (3 * FF) + FF;    // W1d row
            float acc = 0.f;
#pragma unroll 8
            for (int f = 0; f < FF; f += 4) {
                float4 w4 = *(const float4*)(w + f);
                acc += w4.x * px[f] + w4.y * px[f + 1] + w4.z * px[f + 2] + w4.w * px[f + 3];
            }
            pxd[blk * KP + tid] = acc;
        } else if (tid >= KH && tid < KP) {
            pxd[blk * KP + tid] = 0.f;                    // pad
        } else if (tid >= 128 && tid < 128 + KH) {
            int k = tid - 128;
            const float* w = W1 + k * (3 * FF) + 2 * FF;  // W1e row
            float acc = 0.f;
#pragma unroll 8
            for (int f = 0; f < FF; f += 4) {
                float4 w4 = *(const float4*)(w + f);
                acc += w4.x * px[f] + w4.y * px[f + 1] + w4.z * px[f + 2] + w4.w * px[f + 3];
            }
            pxe[blk * KP + k] = acc;
        } else if (tid >= 128 + KH && tid < 128 + KP) {
            pxe[blk * KP + (tid - 128)] = 0.f;            // pad
        }
    } else {
        // ---- heads path ----
        int hb = blk - BB * NN;         // b*S + t
        int ts = hb % SS, b = hb / SS;
        __shared__ __align__(16) float prc[FF], prb[FF];
        __shared__ __align__(16) float uc[KH], ub[KH];
        float ac1 = ac1p[0], ab1 = ab1p[0];
        float rv = rnn[(b * SS + ts) * FF + tid];
        prc[tid] = prelu_f(rv, ac1);
        prb[tid] = prelu_f(rv, ab1);
        __syncthreads();
        if (tid < KH) {
            const float* wc = Wc1 + tid * FF;
            float ac = 0.f;
#pragma unroll 8
            for (int f = 0; f < FF; f += 4) {
                float4 c4 = *(const float4*)(wc + f);
                ac += c4.x * prc[f] + c4.y * prc[f + 1] + c4.z * prc[f + 2] + c4.w * prc[f + 3];
            }
            uc[tid] = prelu_f(ac + bc1[tid], ac2p[0]);
        } else if (tid >= 128 && tid < 128 + KH) {
            int k = tid - 128;
            const float* wb = Wb1 + k * FF;
            float ab = 0.f;
#pragma unroll 8
            for (int f = 0; f < FF; f += 4) {
                float4 b4 = *(const float4*)(wb + f);
                ab += b4.x * prb[f] + b4.y * prb[f + 1] + b4.z * prb[f + 2] + b4.w * prb[f + 3];
            }
            ub[k] = prelu_f(ab + bb1[k], ab2p[0]);
        }
        __syncthreads();
        if (tid < NCLS) {
            const float* w = Wc2 + tid * KH;
            float acc = bc2[tid];
#pragma unroll
            for (int q = 0; q < KH; q += 4) {
                float4 w4 = *(const float4*)(w + q);
                acc += w4.x * uc[q] + w4.y * uc[q + 1] + w4.z * uc[q + 2] + w4.w * uc[q + 3];
            }
            cls_out[(b * SS + ts) * NCLS + tid] = acc;
        }
        if (tid >= 64 && tid < 66) {
            int o = tid - 64;
            const float* w = Wb2 + o * KH;
            float acc = bb2[o];
#pragma unroll
            for (int q = 0; q < KH; q += 4) {
                float4 w4 = *(const float4*)(w + q);
                acc += w4.x * ub[q] + w4.y * ub[q + 1] + w4.z * ub[q + 2] + w4.w * ub[q + 3];
            }
            bin_out[(b * SS + ts) * 2 + o] = acc;
        }
    }
}

// ---------------- K5: scores via MFMA (bf16 hi/lo split A, bf16 W) ---------
#define JT 32
#define JTILES 13
#define AP 264          // row stride in shorts (256 + 8 pad)
__global__ __launch_bounds__(256, 2)
void k_scores(const float* __restrict__ cum,
              const short* __restrict__ wh, const short* __restrict__ wl,
              const float* __restrict__ pxd, const float* __restrict__ pxe,
              const float* __restrict__ b1p, const float* __restrict__ w2p,
              const float* __restrict__ b2p,
              const float* __restrict__ a1p, const float* __restrict__ a2p,
              float* __restrict__ scores, float* __restrict__ scoresT) {
    int blk = blockIdx.x;
    int jt = blk % JTILES;
    int i = (blk / JTILES) % NN;
    int b = blk / (JTILES * NN);
    int tid = threadIdx.x;
    float a1 = a1p[0], a2 = a2p[0];
    int jbase = jt * JT;

    __shared__ __align__(16) float ci[FF];
    __shared__ __align__(16) short dth[JT][AP];
    __shared__ __align__(16) short dtl[JT][AP];
    __shared__ float red[4][JT];

    ci[tid] = cum[(b * NN + i) * FF + tid];
    __syncthreads();

    {
        int row = tid >> 3;
        int fb = (tid & 7) * 32;
        int jg = jbase + row;
        int jc = (jg <= SS) ? jg : SS;
        const float* cj = cum + (b * NN + jc) * FF + fb;
#pragma unroll
        for (int c8 = 0; c8 < 4; ++c8) {
            float4 v0 = *(const float4*)(cj + c8 * 8);
            float4 v1 = *(const float4*)(cj + c8 * 8 + 4);
            union { short8 s; unsigned short u[8]; } h8, l8;
            float dv[8] = { v0.x, v0.y, v0.z, v0.w, v1.x, v1.y, v1.z, v1.w };
#pragma unroll
            for (int e = 0; e < 8; ++e) {
                float d = prelu_f(dv[e] - ci[fb + c8 * 8 + e], a1);
                unsigned short hi = f2bf(d);
                h8.u[e] = hi;
                l8.u[e] = f2bf(d - bf2f(hi));
            }
            *(short8*)(&dth[row][fb + c8 * 8]) = h8.s;
            *(short8*)(&dtl[row][fb + c8 * 8]) = l8.s;
        }
    }
    __syncthreads();

    int lane = tid & 63;
    int wv = tid >> 6;
    int quad = lane >> 4;
    int l15 = lane & 15;
    int kt0 = wv * 2, kt1 = wv * 2 + 1;
    bool has1 = (kt1 < 7);

    short8 bh0[8], bl0[8], bh1[8], bl1[8];
    {
        const short8* ph0 = (const short8*)(wh + (kt0 * 16 + l15) * FF);
        const short8* pl0 = (const short8*)(wl + (kt0 * 16 + l15) * FF);
        int k1row = has1 ? (kt1 * 16 + l15) : 0;
        const short8* ph1 = (const short8*)(wh + k1row * FF);
        const short8* pl1 = (const short8*)(wl + k1row * FF);
#pragma unroll
        for (int ks = 0; ks < 8; ++ks) {
            bh0[ks] = ph0[ks * 4 + quad];
            bl0[ks] = pl0[ks * 4 + quad];
            bh1[ks] = ph1[ks * 4 + quad];
            bl1[ks] = pl1[ks * 4 + quad];
        }
    }

    int kout0 = kt0 * 16 + l15;
    int kout1 = has1 ? (kt1 * 16 + l15) : 0;
    float pd0 = pxd[(b * NN + i) * KP + kout0];
    float pd1 = pxd[(b * NN + i) * KP + kout1];
    float bb0 = b1p[kout0], bb1v = b1p[kout1];
    float w20 = w2p[kout0];
    float w21 = has1 ? w2p[kout1] : 0.f;

#pragma unroll
    for (int mt = 0; mt < 2; ++mt) {
        short8 ah[8], al[8];
        {
            int arow = mt * 16 + l15;
            const short* base_h = &dth[0][0] + arow * AP;
            const short* base_l = &dtl[0][0] + arow * AP;
#pragma unroll
            for (int ks = 0; ks < 8; ++ks) {
                ah[ks] = *(const short8*)(base_h + ks * 32 + quad * 8);
                al[ks] = *(const short8*)(base_l + ks * 32 + quad * 8);
            }
        }
        f32x4 acc0 = {0.f, 0.f, 0.f, 0.f};
        f32x4 acc1 = {0.f, 0.f, 0.f, 0.f};
#pragma unroll
        for (int ks = 0; ks < 8; ++ks) {
            acc0 = __builtin_amdgcn_mfma_f32_16x16x32_bf16(ah[ks], bh0[ks], acc0, 0, 0, 0);
            acc0 = __builtin_amdgcn_mfma_f32_16x16x32_bf16(al[ks], bl0[ks], acc0, 0, 0, 0);
            if (has1) {
                acc1 = __builtin_amdgcn_mfma_f32_16x16x32_bf16(ah[ks], bh1[ks], acc1, 0, 0, 0);
                acc1 = __builtin_amdgcn_mfma_f32_16x16x32_bf16(al[ks], bl1[ks], acc1, 0, 0, 0);
            }
        }
#pragma unroll
        for (int r = 0; r < 4; ++r) {
            int m = mt * 16 + quad * 4 + r;
            int jg = jbase + m;
            int jc = (jg <= SS) ? jg : SS;
            float pe0 = pxe[(b * NN + jc) * KP + kout0];
            float pe1 = pxe[(b * NN + jc) * KP + kout1];
            float h0 = acc0[r] + pd0 + pe0 + bb0;
            float s = w20 * prelu_f(h0, a2);
            float h1 = acc1[r] + pd1 + pe1 + bb1v;
            s += w21 * prelu_f(h1, a2);
            s += __shfl_xor(s, 1);
            s += __shfl_xor(s, 2);
            s += __shfl_xor(s, 4);
            s += __shfl_xor(s, 8);
            if (l15 == 0) red[wv][m] = s;
        }
    }
    __syncthreads();
    if (tid < JT) {
        int jg = jbase + tid;
        if (jg <= SS) {
            float tot = red[0][tid] + red[1][tid] + red[2][tid] + red[3][tid] + b2p[0];
            scores[(b * NN + i) * NN + jg] = tot;
            scoresT[(b * NN + jg) * NN + i] = tot;   // transposed copy for k_dp
        }
    }
}

// ---------------- K7: DP segment search (single wave, no barriers) ---------
__global__ void k_dp(const float* __restrict__ scoresT, const int* __restrict__ lengths,
                     float* __restrict__ predF, float* __restrict__ prevF) {
    int b = blockIdx.x;
    int lane = threadIdx.x;          // 64 threads = 1 wave: lockstep, no __syncthreads
    __shared__ float bl[BB][NN];
    for (int idx = lane; idx < NN; idx += 64) bl[b][idx] = 0.f;
    if (lane == 0) prevF[b * NN] = 0.f;

    int lo = 0, cnt = 1;
    float sc = (lane < cnt) ? scoresT[(b * NN + 1) * NN + lo + lane] : 0.f;

    for (int i = 1; i <= NN - 1; ++i) {
        int myk = lo + lane;
        float cand = (lane < cnt) ? bl[b][myk] + sc : -INFINITY;
        int idx = myk;
        int lo2 = (i + 1 > MAXSEG) ? (i + 1 - MAXSEG) : 0;
        int cnt2 = i + 1 - lo2;
        float scn = 0.f;
        if (i + 1 <= NN - 1 && lane < cnt2)
            scn = scoresT[(b * NN + (i + 1)) * NN + lo2 + lane];
#pragma unroll
        for (int off = 32; off; off >>= 1) {
            float vo = __shfl_down(cand, off);
            int io = __shfl_down(idx, off);
            if (vo > cand || (vo == cand && io < idx)) { cand = vo; idx = io; }
        }
        if (lane == 0) {
            bl[b][i] = cand;
            prevF[b * NN + i] = (float)idx;
        }
        __builtin_amdgcn_wave_barrier();   // compiler fence only (no HW cost)
        sc = scn;
        lo = lo2; cnt = cnt2;
    }
    if (lane == 0) {
        int len = lengths[b];
        predF[b] = bl[b][len];
    }
}

// ---------------- launch ---------------------------------------------------
extern "C" void kernel_launch(void* const* d_in, const int* in_sizes, int n_in,
                              void* d_out, int out_size, void* d_ws, size_t ws_size,
                              hipStream_t stream) {
    const float* x    = (const float*)d_in[0];
    const int* lengths= (const int*)d_in[1];
    const float* Wi_f = (const float*)d_in[2];
    const float* Wh_f = (const float*)d_in[3];
    const float* b_f  = (const float*)d_in[4];
    const float* Wi_b = (const float*)d_in[5];
    const float* Wh_b = (const float*)d_in[6];
    const float* b_b  = (const float*)d_in[7];
    const float* a1   = (const float*)d_in[8];
    const float* W1   = (const float*)d_in[9];
    const float* b1   = (const float*)d_in[10];
    const float* a2   = (const float*)d_in[11];
    const float* W2   = (const float*)d_in[12];
    const float* b2   = (const float*)d_in[13];
    const float* ac1  = (const float*)d_in[14];
    const float* Wc1  = (const float*)d_in[15];
    const float* bc1  = (const float*)d_in[16];
    const float* ac2  = (const float*)d_in[17];
    const float* Wc2  = (const float*)d_in[18];
    const float* bc2  = (const float*)d_in[19];
    const float* ab1  = (const float*)d_in[20];
    const float* Wb1  = (const float*)d_in[21];
    const float* bb1  = (const float*)d_in[22];
    const float* ab2  = (const float*)d_in[23];
    const float* Wb2  = (const float*)d_in[24];
    const float* bb2  = (const float*)d_in[25];

    float* out = (float*)d_out;
    float* scores = out + SCORES_OFF;
    float* cls    = out + CLS_OFF;
    float* bin    = out + BIN_OFF;
    float* pred   = out + PRED_OFF;
    float* prev   = out + PREV_OFF;

    float* ws   = (float*)d_ws;
    float* gx   = ws + WS_GX;
    float* scoresT = ws + WS_GX;     // reuse: gx dead after k_lstm_rec
    float* rnn  = ws + WS_RNN;
    float* cum  = ws + WS_CUM;
    float* pxd  = ws + WS_PXD;
    float* pxe  = ws + WS_PXE;
    float* part = ws + WS_PART;
    short* wH   = (short*)(ws + WS_WH);
    short* wL   = (short*)(ws + WS_WL);
    float* w2p  = ws + WS_W2P;
    float* b1p  = ws + WS_B1P;
    short* whh  = (short*)(ws + WS_WHH);
    short* whl  = (short*)(ws + WS_WHL);

    k_prep<<<KP, FF, 0, stream>>>(W1, W2, b1, wH, wL, w2p, b1p);
    k_prep_wh<<<2 * G4, HH, 0, stream>>>(Wh_f, Wh_b, whh, whl);
    k_lstm_pre<<<4 * SS, 256, 0, stream>>>(x, Wi_f, b_f, Wi_b, b_b, gx);
    k_lstm_rec<<<2, 256, 0, stream>>>(whh, whl, gx, rnn);
    k_cum_part<<<BB * NCH, FF, 0, stream>>>(rnn, part);
    k_cum_off<<<BB, FF, 0, stream>>>(part);
    k_cum_write<<<BB * NCH, FF, 0, stream>>>(rnn, part, cum);
    k_pxde_heads<<<BB * NN + BB * SS, 256, 0, stream>>>(rnn, W1, a1, pxd, pxe,
                                                        ac1, Wc1, bc1, ac2, Wc2, bc2,
                                                        ab1, Wb1, bb1, ab2, Wb2, bb2,
                                                        cls, bin);
    k_scores<<<BB * NN * JTILES, 256, 0, stream>>>(cum, wH, wL, pxd, pxe, b1p, w2p, b2,
                                                   a1, a2, scores, scoresT);
    k_dp<<<BB, 64, 0, stream>>>(scoresT, lengths, pred, prev);
}

// Round 9
// 948.873 us; speedup vs baseline: 1.2603x; 1.2603x over previous
//
#include <hip/hip_runtime.h>
#include <hip/hip_fp16.h>
#include <math.h>

// Problem constants
#define BB 2
#define SS 400
#define II 80
#define HH 128
#define FF 256          // 2*H
#define NN 401          // S+1
#define G4 512          // 4*H
#define MAXSEG 50
#define NCLS 50
#define KH 100          // rows of W1 / Wc1 / Wb1
#define KP 112          // KH padded to 7*16 for MFMA

// d_out layout (floats): scores | cls | bin | pred | prev
#define SCORES_OFF 0
#define CLS_OFF    (BB*NN*NN)
#define BIN_OFF    (CLS_OFF + BB*SS*NCLS)
#define PRED_OFF   (BIN_OFF + BB*SS*2)
#define PREV_OFF   (PRED_OFF + BB)

// workspace layout (float slots)
#define WS_GX      0                          // 4*S*512 = 819200 (dead after k_lstm_rec;
                                              // reused as scoresT 321602)
#define WS_RNN     (WS_GX + 4*SS*G4)          // B*S*F
#define WS_CUM     (WS_RNN + BB*SS*FF)        // B*N*F
#define WS_PXD     (WS_CUM + BB*NN*FF)        // B*N*KP
#define WS_PXE     (WS_PXD + BB*NN*KP)
#define WS_PART    (WS_PXE + BB*NN*KP)        // B*16*F
#define WS_WH      (WS_PART + BB*16*FF)       // W1c hi bf16: KP*FF shorts
#define WS_WL      (WS_WH + (KP*FF)/2)
#define WS_W2P     (WS_WL + (KP*FF)/2)        // KP floats
#define WS_B1P     (WS_W2P + KP)              // KP floats
#define WS_WHP     (WS_B1P + KP)              // Wh f16: 2*512*128 halves = 65536 floats

typedef __attribute__((ext_vector_type(8))) short short8;
typedef __attribute__((ext_vector_type(4))) float f32x4;
typedef _Float16 f16x2 __attribute__((ext_vector_type(2)));

__device__ __forceinline__ float prelu_f(float x, float a) {
    return x >= 0.f ? x : a * x;
}
__device__ __forceinline__ unsigned short f2bf(float x) {
    union { float f; unsigned u; } v; v.f = x;
    unsigned r = v.u + 0x7fffu + ((v.u >> 16) & 1u);   // RNE
    return (unsigned short)(r >> 16);
}
__device__ __forceinline__ float bf2f(unsigned short h) {
    union { unsigned u; float f; } v; v.u = ((unsigned)h) << 16; return v.f;
}
__device__ __forceinline__ float fast_sigmoid(float x) {
    return 1.f / (1.f + __expf(-x));
}
__device__ __forceinline__ float fast_tanh(float x) {
    return 1.f - 2.f / (1.f + __expf(2.f * x));
}
__device__ __forceinline__ float dot2f(unsigned w, unsigned h, float acc) {
#if __has_builtin(__builtin_amdgcn_fdot2)
    union { unsigned u; f16x2 h; } a, b; a.u = w; b.u = h;
    return __builtin_amdgcn_fdot2(a.h, b.h, acc, false);
#else
    union { unsigned u; _Float16 h[2]; } a, b; a.u = w; b.u = h;
    return acc + (float)a.h[0] * (float)b.h[0] + (float)a.h[1] * (float)b.h[1];
#endif
}

// ---------------- K0: prep W1c bf16 hi/lo + padded W2/b1 -------------------
__global__ void k_prep(const float* __restrict__ W1, const float* __restrict__ W2,
                       const float* __restrict__ b1,
                       short* __restrict__ wh, short* __restrict__ wl,
                       float* __restrict__ w2p, float* __restrict__ b1p) {
    int k = blockIdx.x;        // 0..111
    int f = threadIdx.x;       // 0..255
    float w = (k < KH) ? W1[k * (3 * FF) + f] : 0.f;
    unsigned short hi = f2bf(w);
    unsigned short lo = f2bf(w - bf2f(hi));
    wh[k * FF + f] = (short)hi;
    wl[k * FF + f] = (short)lo;
    if (f == 0) {
        w2p[k] = (k < KH) ? W2[k] : 0.f;
        b1p[k] = (k < KH) ? b1[k] : 0.f;
    }
}

// ---------------- K0b: pack Wh to f16 --------------------------------------
__global__ void k_prep_whf(const float* __restrict__ Wh_f, const float* __restrict__ Wh_b,
                           __half* __restrict__ whp) {
    int blk = blockIdx.x;           // dir*512 + g
    int g = blk & 511;
    int dir = blk >> 9;
    const float* Wh = dir ? Wh_b : Wh_f;
    int k = threadIdx.x;            // 0..127
    whp[(dir * G4 + g) * HH + k] = (__half)Wh[g * HH + k];
}

// ---------------- K1: gx[db][t][g] = b[g] + x[b, xt, :] . Wi[g, :] ---------
__global__ void k_lstm_pre(const float* __restrict__ x,
                           const float* __restrict__ Wi_f, const float* __restrict__ b_f,
                           const float* __restrict__ Wi_b, const float* __restrict__ b_b,
                           float* __restrict__ gx) {
    int blk = blockIdx.x;          // db*S + t
    int t = blk % SS;
    int db = blk / SS;             // dir*2 + b
    int b = db & 1, dir = db >> 1;
    const float* Wi = dir ? Wi_b : Wi_f;
    const float* bias = dir ? b_b : b_f;
    int xt = dir ? (SS - 1 - t) : t;

    __shared__ __align__(16) float xr[II];
    int tid = threadIdx.x;
    if (tid < II) xr[tid] = x[(b * SS + xt) * II + tid];
    __syncthreads();

    for (int g = tid; g < G4; g += 256) {
        const float* w = Wi + g * II;
        float acc = bias[g];
#pragma unroll
        for (int i = 0; i < II; i += 4) {
            float4 w4 = *(const float4*)(w + i);
            acc += w4.x * xr[i] + w4.y * xr[i + 1] + w4.z * xr[i + 2] + w4.w * xr[i + 3];
        }
        gx[(db * SS + t) * G4 + g] = acc;
    }
}

// ---------------- K2: recurrent LSTM, 4 blocks (dir,b), 512 threads --------
// thread = one full gate g (0..511): 64 v_dot2_f32_f16 over f16-pair weights
// in 16 uint4 = 64 VGPRs. With __launch_bounds__(512,2) the VGPR cap is 128;
// demand ~100 -> weights stay in arch VGPRs (R4-R6 demanded ~170 and got
// AGPR-parked; R8's asm pin doesn't compile - unnecessary anyway).
// h is f16 in LDS, read via same-address ds_read_b128 (broadcast, conflict-
// free). No shuffles; gate exchange via one LDS roundtrip. 2 barriers/step.
__global__ __launch_bounds__(512, 2)
void k_lstm_rec(const __half* __restrict__ whp, const float* __restrict__ gx,
                float* __restrict__ rnn_out) {
    int db = blockIdx.x;
    int b = db & 1, dir = db >> 1;
    int tid = threadIdx.x;          // = gate id g

    uint4 w[16];
    {
        const uint4* wp = (const uint4*)(whp + (dir * G4 + tid) * HH);
#pragma unroll
        for (int c = 0; c < 16; ++c) w[c] = wp[c];
    }

    __shared__ __align__(16) __half hsf[2][144];   // 128 h + pad
    __shared__ float gsh[G4];
    for (int i = tid; i < 2 * 144; i += 512) (&hsf[0][0])[i] = (__half)0.f;
    float c_state = 0.f;
    __syncthreads();

    const float* gxp = gx + db * SS * G4;
    float gcur = gxp[tid];                     // prefetch step 0
    int pb = 0;
    for (int step = 0; step < SS; ++step) {
        float gnext = (step + 1 < SS) ? gxp[(step + 1) * G4 + tid] : 0.f;
        const uint4* hp = (const uint4*)(&hsf[pb][0]);
        float a0 = 0.f, a1 = 0.f, a2 = 0.f, a3 = 0.f;
#pragma unroll
        for (int c = 0; c < 16; ++c) {
            uint4 hq = hp[c];
            a0 = dot2f(w[c].x, hq.x, a0);
            a1 = dot2f(w[c].y, hq.y, a1);
            a2 = dot2f(w[c].z, hq.z, a2);
            a3 = dot2f(w[c].w, hq.w, a3);
        }
        gsh[tid] = (a0 + a1) + (a2 + a3) + gcur;
        __syncthreads();
        if (tid < HH) {
            float gi = gsh[tid], gf = gsh[HH + tid];
            float gg = gsh[2 * HH + tid], go = gsh[3 * HH + tid];
            c_state = fast_sigmoid(gf) * c_state + fast_sigmoid(gi) * fast_tanh(gg);
            float h = fast_sigmoid(go) * fast_tanh(c_state);
            hsf[pb ^ 1][tid] = (__half)h;
            int xt = dir ? (SS - 1 - step) : step;
            rnn_out[(b * SS + xt) * FF + dir * HH + tid] = h;
        }
        __syncthreads();
        pb ^= 1;
        gcur = gnext;
    }
}

// ---------------- K3: cumsum over time (3 passes) --------------------------
#define CHUNK 25
#define NCH 16
__global__ void k_cum_part(const float* __restrict__ rnn, float* __restrict__ part) {
    int blk = blockIdx.x;           // b*NCH + c
    int c = blk % NCH, b = blk / NCH;
    int f = threadIdx.x;
    float s = 0.f;
    for (int r = 0; r < CHUNK; ++r) s += rnn[(b * SS + c * CHUNK + r) * FF + f];
    part[blk * FF + f] = s;
}
__global__ void k_cum_off(float* __restrict__ part) {
    int b = blockIdx.x;
    int f = threadIdx.x;
    float run = 0.f;
    for (int c = 0; c < NCH; ++c) {
        int idx = (b * NCH + c) * FF + f;
        float tmp = part[idx];
        part[idx] = run;
        run += tmp;
    }
}
__global__ void k_cum_write(const float* __restrict__ rnn, const float* __restrict__ part,
                            float* __restrict__ cum) {
    int blk = blockIdx.x;           // b*NCH + c
    int c = blk % NCH, b = blk / NCH;
    int f = threadIdx.x;
    float run = part[blk * FF + f];
    cum[(b * NN + c * CHUNK) * FF + f] = run;
    for (int idx = 1; idx <= CHUNK; ++idx) {
        run += rnn[(b * SS + c * CHUNK + idx - 1) * FF + f];
        cum[(b * NN + c * CHUNK + idx) * FF + f] = run;
    }
}

// ---------------- K4: fused pxd/pxe (blk<802) + cls/bin heads (blk>=802) ---
__global__ void k_pxde_heads(const float* __restrict__ rnn, const float* __restrict__ W1,
                             const float* __restrict__ a1p,
                             float* __restrict__ pxd, float* __restrict__ pxe,
                             const float* __restrict__ ac1p, const float* __restrict__ Wc1,
                             const float* __restrict__ bc1, const float* __restrict__ ac2p,
                             const float* __restrict__ Wc2, const float* __restrict__ bc2,
                             const float* __restrict__ ab1p, const float* __restrict__ Wb1,
                             const float* __restrict__ bb1, const float* __restrict__ ab2p,
                             const float* __restrict__ Wb2, const float* __restrict__ bb2,
                             float* __restrict__ cls_out, float* __restrict__ bin_out) {
    int blk = blockIdx.x;
    int tid = threadIdx.x;
    if (blk < BB * NN) {
        int n = blk % NN, b = blk / NN;
        float a1 = a1p[0];
        __shared__ __align__(16) float px[FF];
        float rv = (n == 0) ? 0.f : rnn[(b * SS + n - 1) * FF + tid];
        px[tid] = prelu_f(rv, a1);
        __syncthreads();

        if (tid < KH) {
            const float* w = W1 + tid * (3 * FF) + FF;    // W1d row
            float acc = 0.f;
#pragma unroll 8
            for (int f = 0; f < FF; f += 4) {
                float4 w4 = *(const float4*)(w + f);
                acc += w4.x * px[f] + w4.y * px[f + 1] + w4.z * px[f + 2] + w4.w * px[f + 3];
            }
            pxd[blk * KP + tid] = acc;
        } else if (tid >= KH && tid < KP) {
            pxd[blk * KP + tid] = 0.f;
        } else if (tid >= 128 && tid < 128 + KH) {
            int k = tid - 128;
            const float* w = W1 + k * (3 * FF) + 2 * FF;  // W1e row
            float acc = 0.f;
#pragma unroll 8
            for (int f = 0; f < FF; f += 4) {
                float4 w4 = *(const float4*)(w + f);
                acc += w4.x * px[f] + w4.y * px[f + 1] + w4.z * px[f + 2] + w4.w * px[f + 3];
            }
            pxe[blk * KP + k] = acc;
        } else if (tid >= 128 + KH && tid < 128 + KP) {
            pxe[blk * KP + (tid - 128)] = 0.f;
        }
    } else {
        int hb = blk - BB * NN;         // b*S + t
        int ts = hb % SS, b = hb / SS;
        __shared__ __align__(16) float prc[FF], prb[FF];
        __shared__ __align__(16) float uc[KH], ub[KH];
        float ac1 = ac1p[0], ab1 = ab1p[0];
        float rv = rnn[(b * SS + ts) * FF + tid];
        prc[tid] = prelu_f(rv, ac1);
        prb[tid] = prelu_f(rv, ab1);
        __syncthreads();
        if (tid < KH) {
            const float* wc = Wc1 + tid * FF;
            float ac = 0.f;
#pragma unroll 8
            for (int f = 0; f < FF; f += 4) {
                float4 c4 = *(const float4*)(wc + f);
                ac += c4.x * prc[f] + c4.y * prc[f + 1] + c4.z * prc[f + 2] + c4.w * prc[f + 3];
            }
            uc[tid] = prelu_f(ac + bc1[tid], ac2p[0]);
        } else if (tid >= 128 && tid < 128 + KH) {
            int k = tid - 128;
            const float* wb = Wb1 + k * FF;
            float ab = 0.f;
#pragma unroll 8
            for (int f = 0; f < FF; f += 4) {
                float4 b4 = *(const float4*)(wb + f);
                ab += b4.x * prb[f] + b4.y * prb[f + 1] + b4.z * prb[f + 2] + b4.w * prb[f + 3];
            }
            ub[k] = prelu_f(ab + bb1[k], ab2p[0]);
        }
        __syncthreads();
        if (tid < NCLS) {
            const float* w = Wc2 + tid * KH;
            float acc = bc2[tid];
#pragma unroll
            for (int q = 0; q < KH; q += 4) {
                float4 w4 = *(const float4*)(w + q);
                acc += w4.x * uc[q] + w4.y * uc[q + 1] + w4.z * uc[q + 2] + w4.w * uc[q + 3];
            }
            cls_out[(b * SS + ts) * NCLS + tid] = acc;
        }
        if (tid >= 64 && tid < 66) {
            int o = tid - 64;
            const float* w = Wb2 + o * KH;
            float acc = bb2[o];
#pragma unroll
            for (int q = 0; q < KH; q += 4) {
                float4 w4 = *(const float4*)(w + q);
                acc += w4.x * ub[q] + w4.y * ub[q + 1] + w4.z * ub[q + 2] + w4.w * ub[q + 3];
            }
            bin_out[(b * SS + ts) * 2 + o] = acc;
        }
    }
}

// ---------------- K5: scores via MFMA (bf16 hi/lo split A, bf16 W) ---------
#define JT 32
#define JTILES 13
#define AP 264          // row stride in shorts (256 + 8 pad)
__global__ __launch_bounds__(256, 2)
void k_scores(const float* __restrict__ cum,
              const short* __restrict__ wh, const short* __restrict__ wl,
              const float* __restrict__ pxd, const float* __restrict__ pxe,
              const float* __restrict__ b1p, const float* __restrict__ w2p,
              const float* __restrict__ b2p,
              const float* __restrict__ a1p, const float* __restrict__ a2p,
              float* __restrict__ scores, float* __restrict__ scoresT) {
    int blk = blockIdx.x;
    int jt = blk % JTILES;
    int i = (blk / JTILES) % NN;
    int b = blk / (JTILES * NN);
    int tid = threadIdx.x;
    float a1 = a1p[0], a2 = a2p[0];
    int jbase = jt * JT;

    __shared__ __align__(16) float ci[FF];
    __shared__ __align__(16) short dth[JT][AP];
    __shared__ __align__(16) short dtl[JT][AP];
    __shared__ float red[4][JT];

    ci[tid] = cum[(b * NN + i) * FF + tid];
    __syncthreads();

    {
        int row = tid >> 3;
        int fb = (tid & 7) * 32;
        int jg = jbase + row;
        int jc = (jg <= SS) ? jg : SS;
        const float* cj = cum + (b * NN + jc) * FF + fb;
#pragma unroll
        for (int c8 = 0; c8 < 4; ++c8) {
            float4 v0 = *(const float4*)(cj + c8 * 8);
            float4 v1 = *(const float4*)(cj + c8 * 8 + 4);
            union { short8 s; unsigned short u[8]; } h8, l8;
            float dv[8] = { v0.x, v0.y, v0.z, v0.w, v1.x, v1.y, v1.z, v1.w };
#pragma unroll
            for (int e = 0; e < 8; ++e) {
                float d = prelu_f(dv[e] - ci[fb + c8 * 8 + e], a1);
                unsigned short hi = f2bf(d);
                h8.u[e] = hi;
                l8.u[e] = f2bf(d - bf2f(hi));
            }
            *(short8*)(&dth[row][fb + c8 * 8]) = h8.s;
            *(short8*)(&dtl[row][fb + c8 * 8]) = l8.s;
        }
    }
    __syncthreads();

    int lane = tid & 63;
    int wv = tid >> 6;
    int quad = lane >> 4;
    int l15 = lane & 15;
    int kt0 = wv * 2, kt1 = wv * 2 + 1;
    bool has1 = (kt1 < 7);

    short8 bh0[8], bl0[8], bh1[8], bl1[8];
    {
        const short8* ph0 = (const short8*)(wh + (kt0 * 16 + l15) * FF);
        const short8* pl0 = (const short8*)(wl + (kt0 * 16 + l15) * FF);
        int k1row = has1 ? (kt1 * 16 + l15) : 0;
        const short8* ph1 = (const short8*)(wh + k1row * FF);
        const short8* pl1 = (const short8*)(wl + k1row * FF);
#pragma unroll
        for (int ks = 0; ks < 8; ++ks) {
            bh0[ks] = ph0[ks * 4 + quad];
            bl0[ks] = pl0[ks * 4 + quad];
            bh1[ks] = ph1[ks * 4 + quad];
            bl1[ks] = pl1[ks * 4 + quad];
        }
    }

    int kout0 = kt0 * 16 + l15;
    int kout1 = has1 ? (kt1 * 16 + l15) : 0;
    float pd0 = pxd[(b * NN + i) * KP + kout0];
    float pd1 = pxd[(b * NN + i) * KP + kout1];
    float bb0 = b1p[kout0], bb1v = b1p[kout1];
    float w20 = w2p[kout0];
    float w21 = has1 ? w2p[kout1] : 0.f;

#pragma unroll
    for (int mt = 0; mt < 2; ++mt) {
        short8 ah[8], al[8];
        {
            int arow = mt * 16 + l15;
            const short* base_h = &dth[0][0] + arow * AP;
            const short* base_l = &dtl[0][0] + arow * AP;
#pragma unroll
            for (int ks = 0; ks < 8; ++ks) {
                ah[ks] = *(const short8*)(base_h + ks * 32 + quad * 8);
                al[ks] = *(const short8*)(base_l + ks * 32 + quad * 8);
            }
        }
        f32x4 acc0 = {0.f, 0.f, 0.f, 0.f};
        f32x4 acc1 = {0.f, 0.f, 0.f, 0.f};
#pragma unroll
        for (int ks = 0; ks < 8; ++ks) {
            acc0 = __builtin_amdgcn_mfma_f32_16x16x32_bf16(ah[ks], bh0[ks], acc0, 0, 0, 0);
            acc0 = __builtin_amdgcn_mfma_f32_16x16x32_bf16(al[ks], bl0[ks], acc0, 0, 0, 0);
            if (has1) {
                acc1 = __builtin_amdgcn_mfma_f32_16x16x32_bf16(ah[ks], bh1[ks], acc1, 0, 0, 0);
                acc1 = __builtin_amdgcn_mfma_f32_16x16x32_bf16(al[ks], bl1[ks], acc1, 0, 0, 0);
            }
        }
#pragma unroll
        for (int r = 0; r < 4; ++r) {
            int m = mt * 16 + quad * 4 + r;
            int jg = jbase + m;
            int jc = (jg <= SS) ? jg : SS;
            float pe0 = pxe[(b * NN + jc) * KP + kout0];
            float pe1 = pxe[(b * NN + jc) * KP + kout1];
            float h0 = acc0[r] + pd0 + pe0 + bb0;
            float s = w20 * prelu_f(h0, a2);
            float h1 = acc1[r] + pd1 + pe1 + bb1v;
            s += w21 * prelu_f(h1, a2);
            s += __shfl_xor(s, 1);
            s += __shfl_xor(s, 2);
            s += __shfl_xor(s, 4);
            s += __shfl_xor(s, 8);
            if (l15 == 0) red[wv][m] = s;
        }
    }
    __syncthreads();
    if (tid < JT) {
        int jg = jbase + tid;
        if (jg <= SS) {
            float tot = red[0][tid] + red[1][tid] + red[2][tid] + red[3][tid] + b2p[0];
            scores[(b * NN + i) * NN + jg] = tot;
            scoresT[(b * NN + jg) * NN + i] = tot;   // transposed copy for k_dp
        }
    }
}

// ---------------- K7: DP segment search (single wave, no barriers) ---------
__global__ void k_dp(const float* __restrict__ scoresT, const int* __restrict__ lengths,
                     float* __restrict__ predF, float* __restrict__ prevF) {
    int b = blockIdx.x;
    int lane = threadIdx.x;          // 64 threads = 1 wave: lockstep
    __shared__ float bl[BB][NN];
    for (int idx = lane; idx < NN; idx += 64) bl[b][idx] = 0.f;
    if (lane == 0) prevF[b * NN] = 0.f;

    int lo = 0, cnt = 1;
    float sc = (lane < cnt) ? scoresT[(b * NN + 1) * NN + lo + lane] : 0.f;

    for (int i = 1; i <= NN - 1; ++i) {
        int myk = lo + lane;
        float cand = (lane < cnt) ? bl[b][myk] + sc : -INFINITY;
        int idx = myk;
        int lo2 = (i + 1 > MAXSEG) ? (i + 1 - MAXSEG) : 0;
        int cnt2 = i + 1 - lo2;
        float scn = 0.f;
        if (i + 1 <= NN - 1 && lane < cnt2)
            scn = scoresT[(b * NN + (i + 1)) * NN + lo2 + lane];
#pragma unroll
        for (int off = 32; off; off >>= 1) {
            float vo = __shfl_down(cand, off);
            int io = __shfl_down(idx, off);
            if (vo > cand || (vo == cand && io < idx)) { cand = vo; idx = io; }
        }
        if (lane == 0) {
            bl[b][i] = cand;
            prevF[b * NN + i] = (float)idx;
        }
        __builtin_amdgcn_wave_barrier();
        sc = scn;
        lo = lo2; cnt = cnt2;
    }
    if (lane == 0) {
        int len = lengths[b];
        predF[b] = bl[b][len];
    }
}

// ---------------- launch ---------------------------------------------------
extern "C" void kernel_launch(void* const* d_in, const int* in_sizes, int n_in,
                              void* d_out, int out_size, void* d_ws, size_t ws_size,
                              hipStream_t stream) {
    const float* x    = (const float*)d_in[0];
    const int* lengths= (const int*)d_in[1];
    const float* Wi_f = (const float*)d_in[2];
    const float* Wh_f = (const float*)d_in[3];
    const float* b_f  = (const float*)d_in[4];
    const float* Wi_b = (const float*)d_in[5];
    const float* Wh_b = (const float*)d_in[6];
    const float* b_b  = (const float*)d_in[7];
    const float* a1   = (const float*)d_in[8];
    const float* W1   = (const float*)d_in[9];
    const float* b1   = (const float*)d_in[10];
    const float* a2   = (const float*)d_in[11];
    const float* W2   = (const float*)d_in[12];
    const float* b2   = (const float*)d_in[13];
    const float* ac1  = (const float*)d_in[14];
    const float* Wc1  = (const float*)d_in[15];
    const float* bc1  = (const float*)d_in[16];
    const float* ac2  = (const float*)d_in[17];
    const float* Wc2  = (const float*)d_in[18];
    const float* bc2  = (const float*)d_in[19];
    const float* ab1  = (const float*)d_in[20];
    const float* Wb1  = (const float*)d_in[21];
    const float* bb1  = (const float*)d_in[22];
    const float* ab2  = (const float*)d_in[23];
    const float* Wb2  = (const float*)d_in[24];
    const float* bb2  = (const float*)d_in[25];

    float* out = (float*)d_out;
    float* scores = out + SCORES_OFF;
    float* cls    = out + CLS_OFF;
    float* bin    = out + BIN_OFF;
    float* pred   = out + PRED_OFF;
    float* prev   = out + PREV_OFF;

    float* ws   = (float*)d_ws;
    float* gx   = ws + WS_GX;
    float* scoresT = ws + WS_GX;     // reuse: gx dead after k_lstm_rec
    float* rnn  = ws + WS_RNN;
    float* cum  = ws + WS_CUM;
    float* pxd  = ws + WS_PXD;
    float* pxe  = ws + WS_PXE;
    float* part = ws + WS_PART;
    short* wH   = (short*)(ws + WS_WH);
    short* wL   = (short*)(ws + WS_WL);
    float* w2p  = ws + WS_W2P;
    float* b1p  = ws + WS_B1P;
    __half* whp = (__half*)(ws + WS_WHP);

    k_prep<<<KP, FF, 0, stream>>>(W1, W2, b1, wH, wL, w2p, b1p);
    k_prep_whf<<<2 * G4, HH, 0, stream>>>(Wh_f, Wh_b, whp);
    k_lstm_pre<<<4 * SS, 256, 0, stream>>>(x, Wi_f, b_f, Wi_b, b_b, gx);
    k_lstm_rec<<<4, 512, 0, stream>>>(whp, gx, rnn);
    k_cum_part<<<BB * NCH, FF, 0, stream>>>(rnn, part);
    k_cum_off<<<BB, FF, 0, stream>>>(part);
    k_cum_write<<<BB * NCH, FF, 0, stream>>>(rnn, part, cum);
    k_pxde_heads<<<BB * NN + BB * SS, 256, 0, stream>>>(rnn, W1, a1, pxd, pxe,
                                                        ac1, Wc1, bc1, ac2, Wc2, bc2,
                                                        ab1, Wb1, bb1, ab2, Wb2, bb2,
                                                        cls, bin);
    k_scores<<<BB * NN * JTILES, 256, 0, stream>>>(cum, wH, wL, pxd, pxe, b1p, w2p, b2,
                                                   a1, a2, scores, scoresT);
    k_dp<<<BB, 64, 0, stream>>>(scoresT, lengths, pred, prev);
}

// Round 10
// 889.933 us; speedup vs baseline: 1.3437x; 1.0662x over previous
//
#include <hip/hip_runtime.h>
#include <hip/hip_fp16.h>
#include <math.h>

// Problem constants
#define BB 2
#define SS 400
#define II 80
#define HH 128
#define FF 256          // 2*H
#define NN 401          // S+1
#define G4 512          // 4*H
#define MAXSEG 50
#define NCLS 50
#define KH 100          // rows of W1 / Wc1 / Wb1
#define KP 112          // KH padded to 7*16 for MFMA

// d_out layout (floats): scores | cls | bin | pred | prev
#define SCORES_OFF 0
#define CLS_OFF    (BB*NN*NN)
#define BIN_OFF    (CLS_OFF + BB*SS*NCLS)
#define PRED_OFF   (BIN_OFF + BB*SS*2)
#define PREV_OFF   (PRED_OFF + BB)

// workspace layout (float slots)
#define WS_GX      0                          // 4*S*512 = 819200 (dead after k_lstm_rec;
                                              // reused as scoresT 321602)
#define WS_RNN     (WS_GX + 4*SS*G4)          // B*S*F
#define WS_CUM     (WS_RNN + BB*SS*FF)        // B*N*F
#define WS_PXD     (WS_CUM + BB*NN*FF)        // B*N*KP
#define WS_PXE     (WS_PXD + BB*NN*KP)
#define WS_PART    (WS_PXE + BB*NN*KP)        // B*16*F
#define WS_WH      (WS_PART + BB*16*FF)       // W1c hi bf16: KP*FF shorts
#define WS_WL      (WS_WH + (KP*FF)/2)        // (unused since R10)
#define WS_W2P     (WS_WL + (KP*FF)/2)        // KP floats
#define WS_B1P     (WS_W2P + KP)              // KP floats
#define WS_WHP     (WS_B1P + KP)              // Wh f16: 2*512*128 halves

typedef __attribute__((ext_vector_type(8))) short short8;
typedef __attribute__((ext_vector_type(4))) float f32x4;
typedef _Float16 f16x2 __attribute__((ext_vector_type(2)));

__device__ __forceinline__ float prelu_f(float x, float a) {
    return x >= 0.f ? x : a * x;
}
__device__ __forceinline__ unsigned short f2bf(float x) {
    union { float f; unsigned u; } v; v.f = x;
    unsigned r = v.u + 0x7fffu + ((v.u >> 16) & 1u);   // RNE
    return (unsigned short)(r >> 16);
}
__device__ __forceinline__ float fast_sigmoid(float x) {
    return 1.f / (1.f + __expf(-x));
}
__device__ __forceinline__ float fast_tanh(float x) {
    return 1.f - 2.f / (1.f + __expf(2.f * x));
}
__device__ __forceinline__ float dot2f(unsigned w, unsigned h, float acc) {
#if __has_builtin(__builtin_amdgcn_fdot2)
    union { unsigned u; f16x2 h; } a, b; a.u = w; b.u = h;
    return __builtin_amdgcn_fdot2(a.h, b.h, acc, false);
#else
    union { unsigned u; _Float16 h[2]; } a, b; a.u = w; b.u = h;
    return acc + (float)a.h[0] * (float)b.h[0] + (float)a.h[1] * (float)b.h[1];
#endif
}

// ---------------- K0: prep W1c bf16 + padded W2/b1 -------------------------
__global__ void k_prep(const float* __restrict__ W1, const float* __restrict__ W2,
                       const float* __restrict__ b1,
                       short* __restrict__ wh, float* __restrict__ w2p,
                       float* __restrict__ b1p) {
    int k = blockIdx.x;        // 0..111
    int f = threadIdx.x;       // 0..255
    float w = (k < KH) ? W1[k * (3 * FF) + f] : 0.f;
    wh[k * FF + f] = (short)f2bf(w);
    if (f == 0) {
        w2p[k] = (k < KH) ? W2[k] : 0.f;
        b1p[k] = (k < KH) ? b1[k] : 0.f;
    }
}

// ---------------- K0b: pack Wh to f16 --------------------------------------
__global__ void k_prep_whf(const float* __restrict__ Wh_f, const float* __restrict__ Wh_b,
                           __half* __restrict__ whp) {
    int blk = blockIdx.x;           // dir*512 + g
    int g = blk & 511;
    int dir = blk >> 9;
    const float* Wh = dir ? Wh_b : Wh_f;
    int k = threadIdx.x;            // 0..127
    whp[(dir * G4 + g) * HH + k] = (__half)Wh[g * HH + k];
}

// ---------------- K1: gx[db][t][g] = b[g] + x[b, xt, :] . Wi[g, :] ---------
__global__ void k_lstm_pre(const float* __restrict__ x,
                           const float* __restrict__ Wi_f, const float* __restrict__ b_f,
                           const float* __restrict__ Wi_b, const float* __restrict__ b_b,
                           float* __restrict__ gx) {
    int blk = blockIdx.x;          // db*S + t
    int t = blk % SS;
    int db = blk / SS;             // dir*2 + b
    int b = db & 1, dir = db >> 1;
    const float* Wi = dir ? Wi_b : Wi_f;
    const float* bias = dir ? b_b : b_f;
    int xt = dir ? (SS - 1 - t) : t;

    __shared__ __align__(16) float xr[II];
    int tid = threadIdx.x;
    if (tid < II) xr[tid] = x[(b * SS + xt) * II + tid];
    __syncthreads();

    for (int g = tid; g < G4; g += 256) {
        const float* w = Wi + g * II;
        float acc = bias[g];
#pragma unroll
        for (int i = 0; i < II; i += 4) {
            float4 w4 = *(const float4*)(w + i);
            acc += w4.x * xr[i] + w4.y * xr[i + 1] + w4.z * xr[i + 2] + w4.w * xr[i + 3];
        }
        gx[(db * SS + t) * G4 + g] = acc;
    }
}

// ---------------- K2: recurrent LSTM, 4 blocks (dir,b), 512 threads --------
// k-split S=4: lane = (unit q = l>>2, slice s = l&3). Each lane: all 4 gate
// types of unit u over h-slice [32s, 32s+32) -> 64 dot2, 64 weight-VGPRs.
// h read = 4 ds_read_b128/wave (R9 did 16/wave -> DS-pipe-bound at 1536
// cyc/step/CU; this cuts DS ~4x). Butterfly (xor2,xor1) leaves lane s with
// gate type s; quad-gather (3 shfl) + replicated activation (no divergent
// gate phase, no idle waves). ONE barrier/step (double-buffered h).
__global__ __launch_bounds__(512, 2)
void k_lstm_rec(const __half* __restrict__ whp, const float* __restrict__ gx,
                float* __restrict__ rnn_out) {
    int db = blockIdx.x;
    int b = db & 1, dir = db >> 1;
    int tid = threadIdx.x;
    int wid = tid >> 6;          // wave 0..7
    int l = tid & 63;
    int q = l >> 2;              // unit within wave 0..15
    int s = l & 3;               // k-slice; also this lane's final gate type
    int u = wid * 16 + q;        // unit 0..127
    int kbase = s * 32;

    // weights: 4 gate types x 32-h slice -> 4x4 uint4 = 64 VGPRs
    uint4 wreg[4][4];
#pragma unroll
    for (int j = 0; j < 4; ++j) {
        const uint4* wp = (const uint4*)(whp + (dir * G4 + j * 128 + u) * HH + kbase);
#pragma unroll
        for (int c = 0; c < 4; ++c) wreg[j][c] = wp[c];
    }
    int gid = s * 128 + u;       // gate this lane finalizes

    __shared__ __align__(16) __half hsf[2][136];   // 128 h + pad (272B/buf, 16B-mult)
    for (int i = tid; i < 2 * 136; i += 512) (&hsf[0][0])[i] = (__half)0.f;
    float c_state = 0.f;
    __syncthreads();

    const float* gxp = gx + db * SS * G4;
    float gcur = gxp[gid];                     // prefetch step 0
    int pb = 0;
    for (int step = 0; step < SS; ++step) {
        float gnext = (step + 1 < SS) ? gxp[(step + 1) * G4 + gid] : 0.f;
        uint4 hq[4];
        const uint4* hp = (const uint4*)(&hsf[pb][kbase]);
#pragma unroll
        for (int c = 0; c < 4; ++c) hq[c] = hp[c];
        float v[4];
#pragma unroll
        for (int j = 0; j < 4; ++j) {
            float a0 = 0.f, a1 = 0.f, a2 = 0.f, a3 = 0.f;
#pragma unroll
            for (int c = 0; c < 4; ++c) {
                a0 = dot2f(wreg[j][c].x, hq[c].x, a0);
                a1 = dot2f(wreg[j][c].y, hq[c].y, a1);
                a2 = dot2f(wreg[j][c].z, hq[c].z, a2);
                a3 = dot2f(wreg[j][c].w, hq[c].w, a3);
            }
            v[j] = (a0 + a1) + (a2 + a3);
        }
        // butterfly over slices: lane s ends holding gate type s (full sum)
        float u2[2];
#pragma unroll
        for (int j = 0; j < 2; ++j) {
            float snd = (s & 2) ? v[j] : v[j + 2];
            float kp  = (s & 2) ? v[j + 2] : v[j];
            u2[j] = kp + __shfl_xor(snd, 2);
        }
        float snd1 = (s & 1) ? u2[0] : u2[1];
        float kp1  = (s & 1) ? u2[1] : u2[0];
        float gate = kp1 + __shfl_xor(snd1, 1) + gcur;
        // activation: type s (0=i,1=f,2=g(tanh),3=o); tanh(x)=2*sigm(2x)-1
        float xs = (s == 2) ? 2.f * gate : gate;
        float sg = 1.f / (1.f + __expf(-xs));
        float act = (s == 2) ? 2.f * sg - 1.f : sg;
        // quad gather: slot d holds act of type s^d
        float p1 = __shfl_xor(act, 1);
        float p2 = __shfl_xor(act, 2);
        float p3 = __shfl_xor(p1, 2);
        float ai = (s == 0) ? act : (s == 1) ? p1 : (s == 2) ? p2 : p3;
        float af = (s == 1) ? act : (s == 0) ? p1 : (s == 3) ? p2 : p3;
        float ag = (s == 2) ? act : (s == 3) ? p1 : (s == 0) ? p2 : p3;
        float ao = (s == 3) ? act : (s == 2) ? p1 : (s == 1) ? p2 : p3;
        c_state = af * c_state + ai * ag;      // replicated across the quad
        float h = ao * fast_tanh(c_state);
        if (s == 0) {
            hsf[pb ^ 1][u] = (__half)h;
            int xt = dir ? (SS - 1 - step) : step;
            rnn_out[(b * SS + xt) * FF + dir * HH + u] = h;
        }
        __syncthreads();
        pb ^= 1;
        gcur = gnext;
    }
}

// ---------------- K3: cumsum over time (3 passes) --------------------------
#define CHUNK 25
#define NCH 16
__global__ void k_cum_part(const float* __restrict__ rnn, float* __restrict__ part) {
    int blk = blockIdx.x;           // b*NCH + c
    int c = blk % NCH, b = blk / NCH;
    int f = threadIdx.x;
    float s = 0.f;
    for (int r = 0; r < CHUNK; ++r) s += rnn[(b * SS + c * CHUNK + r) * FF + f];
    part[blk * FF + f] = s;
}
__global__ void k_cum_off(float* __restrict__ part) {
    int b = blockIdx.x;
    int f = threadIdx.x;
    float run = 0.f;
    for (int c = 0; c < NCH; ++c) {
        int idx = (b * NCH + c) * FF + f;
        float tmp = part[idx];
        part[idx] = run;
        run += tmp;
    }
}
__global__ void k_cum_write(const float* __restrict__ rnn, const float* __restrict__ part,
                            float* __restrict__ cum) {
    int blk = blockIdx.x;           // b*NCH + c
    int c = blk % NCH, b = blk / NCH;
    int f = threadIdx.x;
    float run = part[blk * FF + f];
    cum[(b * NN + c * CHUNK) * FF + f] = run;
    for (int idx = 1; idx <= CHUNK; ++idx) {
        run += rnn[(b * SS + c * CHUNK + idx - 1) * FF + f];
        cum[(b * NN + c * CHUNK + idx) * FF + f] = run;
    }
}

// ---------------- K4: fused pxd/pxe (blk<802) + cls/bin heads (blk>=802) ---
__global__ void k_pxde_heads(const float* __restrict__ rnn, const float* __restrict__ W1,
                             const float* __restrict__ a1p,
                             float* __restrict__ pxd, float* __restrict__ pxe,
                             const float* __restrict__ ac1p, const float* __restrict__ Wc1,
                             const float* __restrict__ bc1, const float* __restrict__ ac2p,
                             const float* __restrict__ Wc2, const float* __restrict__ bc2,
                             const float* __restrict__ ab1p, const float* __restrict__ Wb1,
                             const float* __restrict__ bb1, const float* __restrict__ ab2p,
                             const float* __restrict__ Wb2, const float* __restrict__ bb2,
                             float* __restrict__ cls_out, float* __restrict__ bin_out) {
    int blk = blockIdx.x;
    int tid = threadIdx.x;
    if (blk < BB * NN) {
        int n = blk % NN, b = blk / NN;
        float a1 = a1p[0];
        __shared__ __align__(16) float px[FF];
        float rv = (n == 0) ? 0.f : rnn[(b * SS + n - 1) * FF + tid];
        px[tid] = prelu_f(rv, a1);
        __syncthreads();

        if (tid < KH) {
            const float* w = W1 + tid * (3 * FF) + FF;    // W1d row
            float acc = 0.f;
#pragma unroll 8
            for (int f = 0; f < FF; f += 4) {
                float4 w4 = *(const float4*)(w + f);
                acc += w4.x * px[f] + w4.y * px[f + 1] + w4.z * px[f + 2] + w4.w * px[f + 3];
            }
            pxd[blk * KP + tid] = acc;
        } else if (tid >= KH && tid < KP) {
            pxd[blk * KP + tid] = 0.f;
        } else if (tid >= 128 && tid < 128 + KH) {
            int k = tid - 128;
            const float* w = W1 + k * (3 * FF) + 2 * FF;  // W1e row
            float acc = 0.f;
#pragma unroll 8
            for (int f = 0; f < FF; f += 4) {
                float4 w4 = *(const float4*)(w + f);
                acc += w4.x * px[f] + w4.y * px[f + 1] + w4.z * px[f + 2] + w4.w * px[f + 3];
            }
            pxe[blk * KP + k] = acc;
        } else if (tid >= 128 + KH && tid < 128 + KP) {
            pxe[blk * KP + (tid - 128)] = 0.f;
        }
    } else {
        int hb = blk - BB * NN;         // b*S + t
        int ts = hb % SS, b = hb / SS;
        __shared__ __align__(16) float prc[FF], prb[FF];
        __shared__ __align__(16) float uc[KH], ub[KH];
        float ac1 = ac1p[0], ab1 = ab1p[0];
        float rv = rnn[(b * SS + ts) * FF + tid];
        prc[tid] = prelu_f(rv, ac1);
        prb[tid] = prelu_f(rv, ab1);
        __syncthreads();
        if (tid < KH) {
            const float* wc = Wc1 + tid * FF;
            float ac = 0.f;
#pragma unroll 8
            for (int f = 0; f < FF; f += 4) {
                float4 c4 = *(const float4*)(wc + f);
                ac += c4.x * prc[f] + c4.y * prc[f + 1] + c4.z * prc[f + 2] + c4.w * prc[f + 3];
            }
            uc[tid] = prelu_f(ac + bc1[tid], ac2p[0]);
        } else if (tid >= 128 && tid < 128 + KH) {
            int k = tid - 128;
            const float* wb = Wb1 + k * FF;
            float ab = 0.f;
#pragma unroll 8
            for (int f = 0; f < FF; f += 4) {
                float4 b4 = *(const float4*)(wb + f);
                ab += b4.x * prb[f] + b4.y * prb[f + 1] + b4.z * prb[f + 2] + b4.w * prb[f + 3];
            }
            ub[k] = prelu_f(ab + bb1[k], ab2p[0]);
        }
        __syncthreads();
        if (tid < NCLS) {
            const float* w = Wc2 + tid * KH;
            float acc = bc2[tid];
#pragma unroll
            for (int q = 0; q < KH; q += 4) {
                float4 w4 = *(const float4*)(w + q);
                acc += w4.x * uc[q] + w4.y * uc[q + 1] + w4.z * uc[q + 2] + w4.w * uc[q + 3];
            }
            cls_out[(b * SS + ts) * NCLS + tid] = acc;
        }
        if (tid >= 64 && tid < 66) {
            int o = tid - 64;
            const float* w = Wb2 + o * KH;
            float acc = bb2[o];
#pragma unroll
            for (int q = 0; q < KH; q += 4) {
                float4 w4 = *(const float4*)(w + q);
                acc += w4.x * ub[q] + w4.y * ub[q + 1] + w4.z * ub[q + 2] + w4.w * ub[q + 3];
            }
            bin_out[(b * SS + ts) * 2 + o] = acc;
        }
    }
}

// ---------------- K5: scores via MFMA (single bf16 — R2-R9's hi/lo pairing
// was AhBh+AlBl, i.e. effectively single-bf16 already at absmax 1.0;
// dropping the lo arrays halves the A-build and cuts MFMA count 2x) --------
#define JT 32
#define JTILES 13
#define AP 264          // row stride in shorts (256 + 8 pad)
__global__ __launch_bounds__(256, 4)
void k_scores(const float* __restrict__ cum,
              const short* __restrict__ wh,
              const float* __restrict__ pxd, const float* __restrict__ pxe,
              const float* __restrict__ b1p, const float* __restrict__ w2p,
              const float* __restrict__ b2p,
              const float* __restrict__ a1p, const float* __restrict__ a2p,
              float* __restrict__ scores, float* __restrict__ scoresT) {
    int blk = blockIdx.x;
    int jt = blk % JTILES;
    int i = (blk / JTILES) % NN;
    int b = blk / (JTILES * NN);
    int tid = threadIdx.x;
    float a1 = a1p[0], a2 = a2p[0];
    int jbase = jt * JT;

    __shared__ __align__(16) float ci[FF];
    __shared__ __align__(16) short dth[JT][AP];
    __shared__ float red[4][JT];

    ci[tid] = cum[(b * NN + i) * FF + tid];
    __syncthreads();

    {
        int row = tid >> 3;
        int fb = (tid & 7) * 32;
        int jg = jbase + row;
        int jc = (jg <= SS) ? jg : SS;
        const float* cj = cum + (b * NN + jc) * FF + fb;
#pragma unroll
        for (int c8 = 0; c8 < 4; ++c8) {
            float4 v0 = *(const float4*)(cj + c8 * 8);
            float4 v1 = *(const float4*)(cj + c8 * 8 + 4);
            union { short8 s; unsigned short u[8]; } h8;
            float dv[8] = { v0.x, v0.y, v0.z, v0.w, v1.x, v1.y, v1.z, v1.w };
#pragma unroll
            for (int e = 0; e < 8; ++e) {
                float d = prelu_f(dv[e] - ci[fb + c8 * 8 + e], a1);
                h8.u[e] = f2bf(d);
            }
            *(short8*)(&dth[row][fb + c8 * 8]) = h8.s;
        }
    }
    __syncthreads();

    int lane = tid & 63;
    int wv = tid >> 6;
    int quad = lane >> 4;
    int l15 = lane & 15;
    int kt0 = wv * 2, kt1 = wv * 2 + 1;
    bool has1 = (kt1 < 7);

    short8 bh0[8], bh1[8];
    {
        const short8* ph0 = (const short8*)(wh + (kt0 * 16 + l15) * FF);
        int k1row = has1 ? (kt1 * 16 + l15) : 0;
        const short8* ph1 = (const short8*)(wh + k1row * FF);
#pragma unroll
        for (int ks = 0; ks < 8; ++ks) {
            bh0[ks] = ph0[ks * 4 + quad];
            bh1[ks] = ph1[ks * 4 + quad];
        }
    }

    int kout0 = kt0 * 16 + l15;
    int kout1 = has1 ? (kt1 * 16 + l15) : 0;
    float pd0 = pxd[(b * NN + i) * KP + kout0];
    float pd1 = pxd[(b * NN + i) * KP + kout1];
    float bb0 = b1p[kout0], bb1v = b1p[kout1];
    float w20 = w2p[kout0];
    float w21 = has1 ? w2p[kout1] : 0.f;

#pragma unroll
    for (int mt = 0; mt < 2; ++mt) {
        short8 ah[8];
        {
            int arow = mt * 16 + l15;
            const short* base_h = &dth[0][0] + arow * AP;
#pragma unroll
            for (int ks = 0; ks < 8; ++ks)
                ah[ks] = *(const short8*)(base_h + ks * 32 + quad * 8);
        }
        f32x4 acc0 = {0.f, 0.f, 0.f, 0.f};
        f32x4 acc1 = {0.f, 0.f, 0.f, 0.f};
#pragma unroll
        for (int ks = 0; ks < 8; ++ks) {
            acc0 = __builtin_amdgcn_mfma_f32_16x16x32_bf16(ah[ks], bh0[ks], acc0, 0, 0, 0);
            if (has1)
                acc1 = __builtin_amdgcn_mfma_f32_16x16x32_bf16(ah[ks], bh1[ks], acc1, 0, 0, 0);
        }
#pragma unroll
        for (int r = 0; r < 4; ++r) {
            int m = mt * 16 + quad * 4 + r;
            int jg = jbase + m;
            int jc = (jg <= SS) ? jg : SS;
            float pe0 = pxe[(b * NN + jc) * KP + kout0];
            float pe1 = pxe[(b * NN + jc) * KP + kout1];
            float h0 = acc0[r] + pd0 + pe0 + bb0;
            float s = w20 * prelu_f(h0, a2);
            float h1 = acc1[r] + pd1 + pe1 + bb1v;
            s += w21 * prelu_f(h1, a2);
            s += __shfl_xor(s, 1);
            s += __shfl_xor(s, 2);
            s += __shfl_xor(s, 4);
            s += __shfl_xor(s, 8);
            if (l15 == 0) red[wv][m] = s;
        }
    }
    __syncthreads();
    if (tid < JT) {
        int jg = jbase + tid;
        if (jg <= SS) {
            float tot = red[0][tid] + red[1][tid] + red[2][tid] + red[3][tid] + b2p[0];
            scores[(b * NN + i) * NN + jg] = tot;
            scoresT[(b * NN + jg) * NN + i] = tot;   // transposed copy for k_dp
        }
    }
}

// ---------------- K7: DP segment search (single wave, no barriers) ---------
__global__ void k_dp(const float* __restrict__ scoresT, const int* __restrict__ lengths,
                     float* __restrict__ predF, float* __restrict__ prevF) {
    int b = blockIdx.x;
    int lane = threadIdx.x;          // 64 threads = 1 wave: lockstep
    __shared__ float bl[BB][NN];
    for (int idx = lane; idx < NN; idx += 64) bl[b][idx] = 0.f;
    if (lane == 0) prevF[b * NN] = 0.f;

    int lo = 0, cnt = 1;
    float sc = (lane < cnt) ? scoresT[(b * NN + 1) * NN + lo + lane] : 0.f;

    for (int i = 1; i <= NN - 1; ++i) {
        int myk = lo + lane;
        float cand = (lane < cnt) ? bl[b][myk] + sc : -INFINITY;
        int idx = myk;
        int lo2 = (i + 1 > MAXSEG) ? (i + 1 - MAXSEG) : 0;
        int cnt2 = i + 1 - lo2;
        float scn = 0.f;
        if (i + 1 <= NN - 1 && lane < cnt2)
            scn = scoresT[(b * NN + (i + 1)) * NN + lo2 + lane];
#pragma unroll
        for (int off = 32; off; off >>= 1) {
            float vo = __shfl_down(cand, off);
            int io = __shfl_down(idx, off);
            if (vo > cand || (vo == cand && io < idx)) { cand = vo; idx = io; }
        }
        if (lane == 0) {
            bl[b][i] = cand;
            prevF[b * NN + i] = (float)idx;
        }
        __builtin_amdgcn_wave_barrier();
        sc = scn;
        lo = lo2; cnt = cnt2;
    }
    if (lane == 0) {
        int len = lengths[b];
        predF[b] = bl[b][len];
    }
}

// ---------------- launch ---------------------------------------------------
extern "C" void kernel_launch(void* const* d_in, const int* in_sizes, int n_in,
                              void* d_out, int out_size, void* d_ws, size_t ws_size,
                              hipStream_t stream) {
    const float* x    = (const float*)d_in[0];
    const int* lengths= (const int*)d_in[1];
    const float* Wi_f = (const float*)d_in[2];
    const float* Wh_f = (const float*)d_in[3];
    const float* b_f  = (const float*)d_in[4];
    const float* Wi_b = (const float*)d_in[5];
    const float* Wh_b = (const float*)d_in[6];
    const float* b_b  = (const float*)d_in[7];
    const float* a1   = (const float*)d_in[8];
    const float* W1   = (const float*)d_in[9];
    const float* b1   = (const float*)d_in[10];
    const float* a2   = (const float*)d_in[11];
    const float* W2   = (const float*)d_in[12];
    const float* b2   = (const float*)d_in[13];
    const float* ac1  = (const float*)d_in[14];
    const float* Wc1  = (const float*)d_in[15];
    const float* bc1  = (const float*)d_in[16];
    const float* ac2  = (const float*)d_in[17];
    const float* Wc2  = (const float*)d_in[18];
    const float* bc2  = (const float*)d_in[19];
    const float* ab1  = (const float*)d_in[20];
    const float* Wb1  = (const float*)d_in[21];
    const float* bb1  = (const float*)d_in[22];
    const float* ab2  = (const float*)d_in[23];
    const float* Wb2  = (const float*)d_in[24];
    const float* bb2  = (const float*)d_in[25];

    float* out = (float*)d_out;
    float* scores = out + SCORES_OFF;
    float* cls    = out + CLS_OFF;
    float* bin    = out + BIN_OFF;
    float* pred   = out + PRED_OFF;
    float* prev   = out + PREV_OFF;

    float* ws   = (float*)d_ws;
    float* gx   = ws + WS_GX;
    float* scoresT = ws + WS_GX;     // reuse: gx dead after k_lstm_rec
    float* rnn  = ws + WS_RNN;
    float* cum  = ws + WS_CUM;
    float* pxd  = ws + WS_PXD;
    float* pxe  = ws + WS_PXE;
    float* part = ws + WS_PART;
    short* wH   = (short*)(ws + WS_WH);
    float* w2p  = ws + WS_W2P;
    float* b1p  = ws + WS_B1P;
    __half* whp = (__half*)(ws + WS_WHP);

    k_prep<<<KP, FF, 0, stream>>>(W1, W2, b1, wH, w2p, b1p);
    k_prep_whf<<<2 * G4, HH, 0, stream>>>(Wh_f, Wh_b, whp);
    k_lstm_pre<<<4 * SS, 256, 0, stream>>>(x, Wi_f, b_f, Wi_b, b_b, gx);
    k_lstm_rec<<<4, 512, 0, stream>>>(whp, gx, rnn);
    k_cum_part<<<BB * NCH, FF, 0, stream>>>(rnn, part);
    k_cum_off<<<BB, FF, 0, stream>>>(part);
    k_cum_write<<<BB * NCH, FF, 0, stream>>>(rnn, part, cum);
    k_pxde_heads<<<BB * NN + BB * SS, 256, 0, stream>>>(rnn, W1, a1, pxd, pxe,
                                                        ac1, Wc1, bc1, ac2, Wc2, bc2,
                                                        ab1, Wb1, bb1, ab2, Wb2, bb2,
                                                        cls, bin);
    k_scores<<<BB * NN * JTILES, 256, 0, stream>>>(cum, wH, pxd, pxe, b1p, w2p, b2,
                                                   a1, a2, scores, scoresT);
    k_dp<<<BB, 64, 0, stream>>>(scoresT, lengths, pred, prev);
}

// Round 11
// 831.627 us; speedup vs baseline: 1.4379x; 1.0701x over previous
//
#include <hip/hip_runtime.h>
#include <hip/hip_fp16.h>
#include <math.h>

// Problem constants
#define BB 2
#define SS 400
#define II 80
#define HH 128
#define FF 256          // 2*H
#define NN 401          // S+1
#define G4 512          // 4*H
#define MAXSEG 50
#define NCLS 50
#define KH 100          // rows of W1 / Wc1 / Wb1
#define KP 112          // KH padded to 7*16 for MFMA

// d_out layout (floats): scores | cls | bin | pred | prev
#define SCORES_OFF 0
#define CLS_OFF    (BB*NN*NN)
#define BIN_OFF    (CLS_OFF + BB*SS*NCLS)
#define PRED_OFF   (BIN_OFF + BB*SS*2)
#define PREV_OFF   (PRED_OFF + BB)

// workspace layout (float slots)
#define WS_GX      0                          // 4*S*512 = 819200 (dead after k_lstm_rec;
                                              // reused as scoresT 321602)
#define WS_RNN     (WS_GX + 4*SS*G4)          // B*S*F
#define WS_CUM     (WS_RNN + BB*SS*FF)        // B*N*F
#define WS_PXD     (WS_CUM + BB*NN*FF)        // B*N*KP
#define WS_PXE     (WS_PXD + BB*NN*KP)
#define WS_PART    (WS_PXE + BB*NN*KP)        // B*16*F
#define WS_WH      (WS_PART + BB*16*FF)       // W1c bf16: KP*FF shorts
#define WS_WL      (WS_WH + (KP*FF)/2)        // (unused)
#define WS_W2P     (WS_WL + (KP*FF)/2)        // KP floats
#define WS_B1P     (WS_W2P + KP)              // KP floats
#define WS_WHP     (WS_B1P + KP)              // Wh f16: 2*512*128 halves

typedef __attribute__((ext_vector_type(8))) short short8;
typedef __attribute__((ext_vector_type(4))) float f32x4;
typedef _Float16 f16x2 __attribute__((ext_vector_type(2)));

__device__ __forceinline__ float prelu_f(float x, float a) {
    return x >= 0.f ? x : a * x;
}
__device__ __forceinline__ unsigned short f2bf(float x) {
    union { float f; unsigned u; } v; v.f = x;
    unsigned r = v.u + 0x7fffu + ((v.u >> 16) & 1u);   // RNE
    return (unsigned short)(r >> 16);
}
__device__ __forceinline__ float fast_sigmoid(float x) {
    return 1.f / (1.f + __expf(-x));
}
__device__ __forceinline__ float fast_tanh(float x) {
    return 1.f - 2.f / (1.f + __expf(2.f * x));
}
__device__ __forceinline__ float dot2f(unsigned w, unsigned h, float acc) {
#if __has_builtin(__builtin_amdgcn_fdot2)
    union { unsigned u; f16x2 h; } a, b; a.u = w; b.u = h;
    return __builtin_amdgcn_fdot2(a.h, b.h, acc, false);
#else
    union { unsigned u; _Float16 h[2]; } a, b; a.u = w; b.u = h;
    return acc + (float)a.h[0] * (float)b.h[0] + (float)a.h[1] * (float)b.h[1];
#endif
}

// ---------------- K0: prep W1c bf16 + padded W2/b1 -------------------------
__global__ void k_prep(const float* __restrict__ W1, const float* __restrict__ W2,
                       const float* __restrict__ b1,
                       short* __restrict__ wh, float* __restrict__ w2p,
                       float* __restrict__ b1p) {
    int k = blockIdx.x;        // 0..111
    int f = threadIdx.x;       // 0..255
    float w = (k < KH) ? W1[k * (3 * FF) + f] : 0.f;
    wh[k * FF + f] = (short)f2bf(w);
    if (f == 0) {
        w2p[k] = (k < KH) ? W2[k] : 0.f;
        b1p[k] = (k < KH) ? b1[k] : 0.f;
    }
}

// ---------------- K0b: pack Wh to f16 --------------------------------------
__global__ void k_prep_whf(const float* __restrict__ Wh_f, const float* __restrict__ Wh_b,
                           __half* __restrict__ whp) {
    int blk = blockIdx.x;           // dir*512 + g
    int g = blk & 511;
    int dir = blk >> 9;
    const float* Wh = dir ? Wh_b : Wh_f;
    int k = threadIdx.x;            // 0..127
    whp[(dir * G4 + g) * HH + k] = (__half)Wh[g * HH + k];
}

// ---------------- K1: gx[db][t][g] = b[g] + x[b, xt, :] . Wi[g, :] ---------
__global__ void k_lstm_pre(const float* __restrict__ x,
                           const float* __restrict__ Wi_f, const float* __restrict__ b_f,
                           const float* __restrict__ Wi_b, const float* __restrict__ b_b,
                           float* __restrict__ gx) {
    int blk = blockIdx.x;          // db*S + t
    int t = blk % SS;
    int db = blk / SS;             // dir*2 + b
    int b = db & 1, dir = db >> 1;
    const float* Wi = dir ? Wi_b : Wi_f;
    const float* bias = dir ? b_b : b_f;
    int xt = dir ? (SS - 1 - t) : t;

    __shared__ __align__(16) float xr[II];
    int tid = threadIdx.x;
    if (tid < II) xr[tid] = x[(b * SS + xt) * II + tid];
    __syncthreads();

    for (int g = tid; g < G4; g += 256) {
        const float* w = Wi + g * II;
        float acc = bias[g];
#pragma unroll
        for (int i = 0; i < II; i += 4) {
            float4 w4 = *(const float4*)(w + i);
            acc += w4.x * xr[i] + w4.y * xr[i + 1] + w4.z * xr[i + 2] + w4.w * xr[i + 3];
        }
        gx[(db * SS + t) * G4 + g] = acc;
    }
}

// ---------------- K2: recurrent LSTM (R9 version — best measured 274 µs) ---
// thread = one full gate g (0..511): 64 v_dot2_f32_f16, f16 weights in 16
// uint4. h f16 in LDS, same-address ds_read_b128 broadcast. No shuffles;
// gate exchange via LDS roundtrip. 2 barriers/step. (R10's S=4 k-split
// regressed: butterfly+replicated-activation VALU > DS savings.)
__global__ __launch_bounds__(512, 2)
void k_lstm_rec(const __half* __restrict__ whp, const float* __restrict__ gx,
                float* __restrict__ rnn_out) {
    int db = blockIdx.x;
    int b = db & 1, dir = db >> 1;
    int tid = threadIdx.x;          // = gate id g

    uint4 w[16];
    {
        const uint4* wp = (const uint4*)(whp + (dir * G4 + tid) * HH);
#pragma unroll
        for (int c = 0; c < 16; ++c) w[c] = wp[c];
    }

    __shared__ __align__(16) __half hsf[2][144];   // 128 h + pad
    __shared__ float gsh[G4];
    for (int i = tid; i < 2 * 144; i += 512) (&hsf[0][0])[i] = (__half)0.f;
    float c_state = 0.f;
    __syncthreads();

    const float* gxp = gx + db * SS * G4;
    float gcur = gxp[tid];                     // prefetch step 0
    int pb = 0;
    for (int step = 0; step < SS; ++step) {
        float gnext = (step + 1 < SS) ? gxp[(step + 1) * G4 + tid] : 0.f;
        const uint4* hp = (const uint4*)(&hsf[pb][0]);
        float a0 = 0.f, a1 = 0.f, a2 = 0.f, a3 = 0.f;
#pragma unroll
        for (int c = 0; c < 16; ++c) {
            uint4 hq = hp[c];
            a0 = dot2f(w[c].x, hq.x, a0);
            a1 = dot2f(w[c].y, hq.y, a1);
            a2 = dot2f(w[c].z, hq.z, a2);
            a3 = dot2f(w[c].w, hq.w, a3);
        }
        gsh[tid] = (a0 + a1) + (a2 + a3) + gcur;
        __syncthreads();
        if (tid < HH) {
            float gi = gsh[tid], gf = gsh[HH + tid];
            float gg = gsh[2 * HH + tid], go = gsh[3 * HH + tid];
            c_state = fast_sigmoid(gf) * c_state + fast_sigmoid(gi) * fast_tanh(gg);
            float h = fast_sigmoid(go) * fast_tanh(c_state);
            hsf[pb ^ 1][tid] = (__half)h;
            int xt = dir ? (SS - 1 - step) : step;
            rnn_out[(b * SS + xt) * FF + dir * HH + tid] = h;
        }
        __syncthreads();
        pb ^= 1;
        gcur = gnext;
    }
}

// ---------------- K3: cumsum over time (3 passes) --------------------------
#define CHUNK 25
#define NCH 16
__global__ void k_cum_part(const float* __restrict__ rnn, float* __restrict__ part) {
    int blk = blockIdx.x;           // b*NCH + c
    int c = blk % NCH, b = blk / NCH;
    int f = threadIdx.x;
    float s = 0.f;
    for (int r = 0; r < CHUNK; ++r) s += rnn[(b * SS + c * CHUNK + r) * FF + f];
    part[blk * FF + f] = s;
}
__global__ void k_cum_off(float* __restrict__ part) {
    int b = blockIdx.x;
    int f = threadIdx.x;
    float run = 0.f;
    for (int c = 0; c < NCH; ++c) {
        int idx = (b * NCH + c) * FF + f;
        float tmp = part[idx];
        part[idx] = run;
        run += tmp;
    }
}
__global__ void k_cum_write(const float* __restrict__ rnn, const float* __restrict__ part,
                            float* __restrict__ cum) {
    int blk = blockIdx.x;           // b*NCH + c
    int c = blk % NCH, b = blk / NCH;
    int f = threadIdx.x;
    float run = part[blk * FF + f];
    cum[(b * NN + c * CHUNK) * FF + f] = run;
    for (int idx = 1; idx <= CHUNK; ++idx) {
        run += rnn[(b * SS + c * CHUNK + idx - 1) * FF + f];
        cum[(b * NN + c * CHUNK + idx) * FF + f] = run;
    }
}

// ---------------- K4: fused pxd/pxe (blk<802) + cls/bin heads (blk>=802) ---
__global__ void k_pxde_heads(const float* __restrict__ rnn, const float* __restrict__ W1,
                             const float* __restrict__ a1p,
                             float* __restrict__ pxd, float* __restrict__ pxe,
                             const float* __restrict__ ac1p, const float* __restrict__ Wc1,
                             const float* __restrict__ bc1, const float* __restrict__ ac2p,
                             const float* __restrict__ Wc2, const float* __restrict__ bc2,
                             const float* __restrict__ ab1p, const float* __restrict__ Wb1,
                             const float* __restrict__ bb1, const float* __restrict__ ab2p,
                             const float* __restrict__ Wb2, const float* __restrict__ bb2,
                             float* __restrict__ cls_out, float* __restrict__ bin_out) {
    int blk = blockIdx.x;
    int tid = threadIdx.x;
    if (blk < BB * NN) {
        int n = blk % NN, b = blk / NN;
        float a1 = a1p[0];
        __shared__ __align__(16) float px[FF];
        float rv = (n == 0) ? 0.f : rnn[(b * SS + n - 1) * FF + tid];
        px[tid] = prelu_f(rv, a1);
        __syncthreads();

        if (tid < KH) {
            const float* w = W1 + tid * (3 * FF) + FF;    // W1d row
            float acc = 0.f;
#pragma unroll 8
            for (int f = 0; f < FF; f += 4) {
                float4 w4 = *(const float4*)(w + f);
                acc += w4.x * px[f] + w4.y * px[f + 1] + w4.z * px[f + 2] + w4.w * px[f + 3];
            }
            pxd[blk * KP + tid] = acc;
        } else if (tid >= KH && tid < KP) {
            pxd[blk * KP + tid] = 0.f;
        } else if (tid >= 128 && tid < 128 + KH) {
            int k = tid - 128;
            const float* w = W1 + k * (3 * FF) + 2 * FF;  // W1e row
            float acc = 0.f;
#pragma unroll 8
            for (int f = 0; f < FF; f += 4) {
                float4 w4 = *(const float4*)(w + f);
                acc += w4.x * px[f] + w4.y * px[f + 1] + w4.z * px[f + 2] + w4.w * px[f + 3];
            }
            pxe[blk * KP + k] = acc;
        } else if (tid >= 128 + KH && tid < 128 + KP) {
            pxe[blk * KP + (tid - 128)] = 0.f;
        }
    } else {
        int hb = blk - BB * NN;         // b*S + t
        int ts = hb % SS, b = hb / SS;
        __shared__ __align__(16) float prc[FF], prb[FF];
        __shared__ __align__(16) float uc[KH], ub[KH];
        float ac1 = ac1p[0], ab1 = ab1p[0];
        float rv = rnn[(b * SS + ts) * FF + tid];
        prc[tid] = prelu_f(rv, ac1);
        prb[tid] = prelu_f(rv, ab1);
        __syncthreads();
        if (tid < KH) {
            const float* wc = Wc1 + tid * FF;
            float ac = 0.f;
#pragma unroll 8
            for (int f = 0; f < FF; f += 4) {
                float4 c4 = *(const float4*)(wc + f);
                ac += c4.x * prc[f] + c4.y * prc[f + 1] + c4.z * prc[f + 2] + c4.w * prc[f + 3];
            }
            uc[tid] = prelu_f(ac + bc1[tid], ac2p[0]);
        } else if (tid >= 128 && tid < 128 + KH) {
            int k = tid - 128;
            const float* wb = Wb1 + k * FF;
            float ab = 0.f;
#pragma unroll 8
            for (int f = 0; f < FF; f += 4) {
                float4 b4 = *(const float4*)(wb + f);
                ab += b4.x * prb[f] + b4.y * prb[f + 1] + b4.z * prb[f + 2] + b4.w * prb[f + 3];
            }
            ub[k] = prelu_f(ab + bb1[k], ab2p[0]);
        }
        __syncthreads();
        if (tid < NCLS) {
            const float* w = Wc2 + tid * KH;
            float acc = bc2[tid];
#pragma unroll
            for (int q = 0; q < KH; q += 4) {
                float4 w4 = *(const float4*)(w + q);
                acc += w4.x * uc[q] + w4.y * uc[q + 1] + w4.z * uc[q + 2] + w4.w * uc[q + 3];
            }
            cls_out[(b * SS + ts) * NCLS + tid] = acc;
        }
        if (tid >= 64 && tid < 66) {
            int o = tid - 64;
            const float* w = Wb2 + o * KH;
            float acc = bb2[o];
#pragma unroll
            for (int q = 0; q < KH; q += 4) {
                float4 w4 = *(const float4*)(w + q);
                acc += w4.x * ub[q] + w4.y * ub[q + 1] + w4.z * ub[q + 2] + w4.w * ub[q + 3];
            }
            bin_out[(b * SS + ts) * 2 + o] = acc;
        }
    }
}

// ---------------- K5: scores via MFMA, B streamed (register-pressure fix) --
// R2-R10 preloaded all B-fragments (up to 128 VGPRs of B alone) -> demand far
// over the launch-bounds cap -> scratch/AGPR churn every block (the hidden
// ~300 µs). Now each ks iteration loads 2 B-frags (global, L2-hot) + 2
// A-frags (LDS) and issues 4 MFMAs into 16 persistent acc regs. Live ~60
// VGPRs < 128 cap at (256,2).
#define JT 32
#define JTILES 13
#define AP 264          // row stride in shorts (256 + 8 pad)
__global__ __launch_bounds__(256, 2)
void k_scores(const float* __restrict__ cum,
              const short* __restrict__ wh,
              const float* __restrict__ pxd, const float* __restrict__ pxe,
              const float* __restrict__ b1p, const float* __restrict__ w2p,
              const float* __restrict__ b2p,
              const float* __restrict__ a1p, const float* __restrict__ a2p,
              float* __restrict__ scores, float* __restrict__ scoresT) {
    int blk = blockIdx.x;
    int jt = blk % JTILES;
    int i = (blk / JTILES) % NN;
    int b = blk / (JTILES * NN);
    int tid = threadIdx.x;
    float a1 = a1p[0], a2 = a2p[0];
    int jbase = jt * JT;

    __shared__ __align__(16) float ci[FF];
    __shared__ __align__(16) short dth[JT][AP];
    __shared__ float red[4][JT];

    ci[tid] = cum[(b * NN + i) * FF + tid];
    __syncthreads();

    {
        int row = tid >> 3;
        int fb = (tid & 7) * 32;
        int jg = jbase + row;
        int jc = (jg <= SS) ? jg : SS;
        const float* cj = cum + (b * NN + jc) * FF + fb;
#pragma unroll
        for (int c8 = 0; c8 < 4; ++c8) {
            float4 v0 = *(const float4*)(cj + c8 * 8);
            float4 v1 = *(const float4*)(cj + c8 * 8 + 4);
            union { short8 s; unsigned short u[8]; } h8;
            float dv[8] = { v0.x, v0.y, v0.z, v0.w, v1.x, v1.y, v1.z, v1.w };
#pragma unroll
            for (int e = 0; e < 8; ++e) {
                float d = prelu_f(dv[e] - ci[fb + c8 * 8 + e], a1);
                h8.u[e] = f2bf(d);
            }
            *(short8*)(&dth[row][fb + c8 * 8]) = h8.s;
        }
    }
    __syncthreads();

    int lane = tid & 63;
    int wv = tid >> 6;
    int quad = lane >> 4;
    int l15 = lane & 15;
    int kt0 = wv * 2, kt1 = wv * 2 + 1;
    bool has1 = (kt1 < 7);

    int kout0 = kt0 * 16 + l15;
    int kout1 = has1 ? (kt1 * 16 + l15) : 0;
    const short8* pb0 = (const short8*)(wh + kout0 * FF);
    const short8* pb1 = (const short8*)(wh + kout1 * FF);
    const short* a0base = &dth[0][0] + l15 * AP;
    const short* a1base = &dth[0][0] + (16 + l15) * AP;

    f32x4 acc00 = {0.f, 0.f, 0.f, 0.f};   // [mt=0][kt0]
    f32x4 acc01 = {0.f, 0.f, 0.f, 0.f};   // [mt=0][kt1]
    f32x4 acc10 = {0.f, 0.f, 0.f, 0.f};   // [mt=1][kt0]
    f32x4 acc11 = {0.f, 0.f, 0.f, 0.f};   // [mt=1][kt1]
#pragma unroll
    for (int ks = 0; ks < 8; ++ks) {
        short8 b0 = pb0[ks * 4 + quad];
        short8 b1v = pb1[ks * 4 + quad];
        short8 af0 = *(const short8*)(a0base + ks * 32 + quad * 8);
        short8 af1 = *(const short8*)(a1base + ks * 32 + quad * 8);
        acc00 = __builtin_amdgcn_mfma_f32_16x16x32_bf16(af0, b0, acc00, 0, 0, 0);
        acc10 = __builtin_amdgcn_mfma_f32_16x16x32_bf16(af1, b0, acc10, 0, 0, 0);
        if (has1) {
            acc01 = __builtin_amdgcn_mfma_f32_16x16x32_bf16(af0, b1v, acc01, 0, 0, 0);
            acc11 = __builtin_amdgcn_mfma_f32_16x16x32_bf16(af1, b1v, acc11, 0, 0, 0);
        }
    }

    float pd0 = pxd[(b * NN + i) * KP + kout0];
    float pd1 = pxd[(b * NN + i) * KP + kout1];
    float bb0 = b1p[kout0], bb1v = b1p[kout1];
    float w20 = w2p[kout0];
    float w21 = has1 ? w2p[kout1] : 0.f;

#pragma unroll
    for (int mt = 0; mt < 2; ++mt) {
        f32x4 acc0 = mt ? acc10 : acc00;
        f32x4 acc1 = mt ? acc11 : acc01;
#pragma unroll
        for (int r = 0; r < 4; ++r) {
            int m = mt * 16 + quad * 4 + r;
            int jg = jbase + m;
            int jc = (jg <= SS) ? jg : SS;
            float pe0 = pxe[(b * NN + jc) * KP + kout0];
            float pe1 = pxe[(b * NN + jc) * KP + kout1];
            float h0 = acc0[r] + pd0 + pe0 + bb0;
            float s = w20 * prelu_f(h0, a2);
            float h1 = acc1[r] + pd1 + pe1 + bb1v;
            s += w21 * prelu_f(h1, a2);
            s += __shfl_xor(s, 1);
            s += __shfl_xor(s, 2);
            s += __shfl_xor(s, 4);
            s += __shfl_xor(s, 8);
            if (l15 == 0) red[wv][m] = s;
        }
    }
    __syncthreads();
    if (tid < JT) {
        int jg = jbase + tid;
        if (jg <= SS) {
            float tot = red[0][tid] + red[1][tid] + red[2][tid] + red[3][tid] + b2p[0];
            scores[(b * NN + i) * NN + jg] = tot;
            scoresT[(b * NN + jg) * NN + i] = tot;   // transposed copy for k_dp
        }
    }
}

// ---------------- K7: DP segment search (single wave, no barriers) ---------
__global__ void k_dp(const float* __restrict__ scoresT, const int* __restrict__ lengths,
                     float* __restrict__ predF, float* __restrict__ prevF) {
    int b = blockIdx.x;
    int lane = threadIdx.x;          // 64 threads = 1 wave: lockstep
    __shared__ float bl[BB][NN];
    for (int idx = lane; idx < NN; idx += 64) bl[b][idx] = 0.f;
    if (lane == 0) prevF[b * NN] = 0.f;

    int lo = 0, cnt = 1;
    float sc = (lane < cnt) ? scoresT[(b * NN + 1) * NN + lo + lane] : 0.f;

    for (int i = 1; i <= NN - 1; ++i) {
        int myk = lo + lane;
        float cand = (lane < cnt) ? bl[b][myk] + sc : -INFINITY;
        int idx = myk;
        int lo2 = (i + 1 > MAXSEG) ? (i + 1 - MAXSEG) : 0;
        int cnt2 = i + 1 - lo2;
        float scn = 0.f;
        if (i + 1 <= NN - 1 && lane < cnt2)
            scn = scoresT[(b * NN + (i + 1)) * NN + lo2 + lane];
#pragma unroll
        for (int off = 32; off; off >>= 1) {
            float vo = __shfl_down(cand, off);
            int io = __shfl_down(idx, off);
            if (vo > cand || (vo == cand && io < idx)) { cand = vo; idx = io; }
        }
        if (lane == 0) {
            bl[b][i] = cand;
            prevF[b * NN + i] = (float)idx;
        }
        __builtin_amdgcn_wave_barrier();
        sc = scn;
        lo = lo2; cnt = cnt2;
    }
    if (lane == 0) {
        int len = lengths[b];
        predF[b] = bl[b][len];
    }
}

// ---------------- launch ---------------------------------------------------
extern "C" void kernel_launch(void* const* d_in, const int* in_sizes, int n_in,
                              void* d_out, int out_size, void* d_ws, size_t ws_size,
                              hipStream_t stream) {
    const float* x    = (const float*)d_in[0];
    const int* lengths= (const int*)d_in[1];
    const float* Wi_f = (const float*)d_in[2];
    const float* Wh_f = (const float*)d_in[3];
    const float* b_f  = (const float*)d_in[4];
    const float* Wi_b = (const float*)d_in[5];
    const float* Wh_b = (const float*)d_in[6];
    const float* b_b  = (const float*)d_in[7];
    const float* a1   = (const float*)d_in[8];
    const float* W1   = (const float*)d_in[9];
    const float* b1   = (const float*)d_in[10];
    const float* a2   = (const float*)d_in[11];
    const float* W2   = (const float*)d_in[12];
    const float* b2   = (const float*)d_in[13];
    const float* ac1  = (const float*)d_in[14];
    const float* Wc1  = (const float*)d_in[15];
    const float* bc1  = (const float*)d_in[16];
    const float* ac2  = (const float*)d_in[17];
    const float* Wc2  = (const float*)d_in[18];
    const float* bc2  = (const float*)d_in[19];
    const float* ab1  = (const float*)d_in[20];
    const float* Wb1  = (const float*)d_in[21];
    const float* bb1  = (const float*)d_in[22];
    const float* ab2  = (const float*)d_in[23];
    const float* Wb2  = (const float*)d_in[24];
    const float* bb2  = (const float*)d_in[25];

    float* out = (float*)d_out;
    float* scores = out + SCORES_OFF;
    float* cls    = out + CLS_OFF;
    float* bin    = out + BIN_OFF;
    float* pred   = out + PRED_OFF;
    float* prev   = out + PREV_OFF;

    float* ws   = (float*)d_ws;
    float* gx   = ws + WS_GX;
    float* scoresT = ws + WS_GX;     // reuse: gx dead after k_lstm_rec
    float* rnn  = ws + WS_RNN;
    float* cum  = ws + WS_CUM;
    float* pxd  = ws + WS_PXD;
    float* pxe  = ws + WS_PXE;
    float* part = ws + WS_PART;
    short* wH   = (short*)(ws + WS_WH);
    float* w2p  = ws + WS_W2P;
    float* b1p  = ws + WS_B1P;
    __half* whp = (__half*)(ws + WS_WHP);

    k_prep<<<KP, FF, 0, stream>>>(W1, W2, b1, wH, w2p, b1p);
    k_prep_whf<<<2 * G4, HH, 0, stream>>>(Wh_f, Wh_b, whp);
    k_lstm_pre<<<4 * SS, 256, 0, stream>>>(x, Wi_f, b_f, Wi_b, b_b, gx);
    k_lstm_rec<<<4, 512, 0, stream>>>(whp, gx, rnn);
    k_cum_part<<<BB * NCH, FF, 0, stream>>>(rnn, part);
    k_cum_off<<<BB, FF, 0, stream>>>(part);
    k_cum_write<<<BB * NCH, FF, 0, stream>>>(rnn, part, cum);
    k_pxde_heads<<<BB * NN + BB * SS, 256, 0, stream>>>(rnn, W1, a1, pxd, pxe,
                                                        ac1, Wc1, bc1, ac2, Wc2, bc2,
                                                        ab1, Wb1, bb1, ab2, Wb2, bb2,
                                                        cls, bin);
    k_scores<<<BB * NN * JTILES, 256, 0, stream>>>(cum, wH, pxd, pxe, b1p, w2p, b2,
                                                   a1, a2, scores, scoresT);
    k_dp<<<BB, 64, 0, stream>>>(scoresT, lengths, pred, prev);
}